// Round 3
// baseline (434.370 us; speedup 1.0000x reference)
//
#include <hip/hip_runtime.h>
#include <hip/hip_bf16.h>
#include <stdint.h>

#define NNODES 10000
#define NEDGES 160000
#define INCH 1024
#define HCH 1024
#define OUTCH 512
#define MPAD 10112           // 79 * 128
#define EPSV 1e-5f
#define NEG 0.1f

typedef unsigned short u16;
typedef __bf16 bf16x8 __attribute__((ext_vector_type(8)));
typedef float f32x4 __attribute__((ext_vector_type(4)));
typedef __attribute__((address_space(1))) unsigned int gu32;
typedef __attribute__((address_space(3))) unsigned int lu32;

#define GL16(g, l) __builtin_amdgcn_global_load_lds((const gu32*)(g), (lu32*)(l), 16, 0, 0)

__device__ __forceinline__ float bf2f(u16 u) {
    union { unsigned int i; float f; } v; v.i = ((unsigned int)u) << 16; return v.f;
}
__device__ __forceinline__ u16 f2bf(float f) {
    union { float f; unsigned int i; } v; v.f = f;
    unsigned int r = v.i + 0x7fffu + ((v.i >> 16) & 1u);
    return (u16)(r >> 16);
}

// ---------- cast x (fp32) -> xn (bf16), unnormalized ----------
__global__ __launch_bounds__(256) void cast_k(const float* __restrict__ x,
                                              u16* __restrict__ xn) {
    int gid = blockIdx.x * 256 + threadIdx.x;
    int e = gid * 4;
    float4 v = *(const float4*)(x + e);
    ushort4 o;
    o.x = f2bf(v.x); o.y = f2bf(v.y); o.z = f2bf(v.z); o.w = f2bf(v.w);
    *(ushort4*)(xn + e) = o;
}

// ---------- GraphNorm stats from bf16 copy: column sum + sum-of-squares ----------
__global__ __launch_bounds__(256) void sumsq_k(const u16* __restrict__ xn,
                                               float* __restrict__ colsum,
                                               float* __restrict__ colsq) {
    int c = threadIdx.x * 4;
    int r0 = blockIdx.x * 16;
    float s0 = 0.f, s1 = 0.f, s2 = 0.f, s3 = 0.f;
    float q0 = 0.f, q1 = 0.f, q2 = 0.f, q3 = 0.f;
#pragma unroll
    for (int r = 0; r < 16; ++r) {
        ushort4 v = *(const ushort4*)(xn + (size_t)(r0 + r) * INCH + c);
        float f0 = bf2f(v.x), f1 = bf2f(v.y), f2 = bf2f(v.z), f3 = bf2f(v.w);
        s0 += f0; s1 += f1; s2 += f2; s3 += f3;
        q0 += f0 * f0; q1 += f1 * f1; q2 += f2 * f2; q3 += f3 * f3;
    }
    atomicAdd(&colsum[c + 0], s0); atomicAdd(&colsum[c + 1], s1);
    atomicAdd(&colsum[c + 2], s2); atomicAdd(&colsum[c + 3], s3);
    atomicAdd(&colsq[c + 0], q0); atomicAdd(&colsq[c + 1], q1);
    atomicAdd(&colsq[c + 2], q2); atomicAdd(&colsq[c + 3], q3);
}

// ---------- per-column scale/shift ----------
// var = E[x^2] - g*(2-g)*mean^2 ; sc = rsqrt(var+eps)*w ; sh = b - g*mean*sc
__global__ void scale_k(const float* __restrict__ colsum, const float* __restrict__ colsq,
                        const float* __restrict__ gms, const float* __restrict__ gw,
                        const float* __restrict__ gb,
                        float* __restrict__ sc, float* __restrict__ sh) {
    int c = blockIdx.x * 256 + threadIdx.x;
    const float invn = 1.0f / NNODES;
    float m = colsum[c] * invn;
    float msq = colsq[c] * invn;
    float g = gms[c];
    float var = msq - g * (2.0f - g) * m * m;
    float s = rsqrtf(var + EPSV) * gw[c];
    sc[c] = s;
    sh[c] = gb[c] - g * m * s;
}

// ---------- rank-1 correction vector: c1[j] = sum_k sh[k] * W1[k,j] ----------
__global__ void c1_k(const float* __restrict__ W1, const float* __restrict__ sh,
                     float* __restrict__ c1) {
    int j = blockIdx.x * 256 + threadIdx.x;
    int k0 = blockIdx.y * 128;
    float a = 0.f;
#pragma unroll 4
    for (int k = k0; k < k0 + 128; ++k) a += sh[k] * W1[(size_t)k * HCH + j];
    atomicAdd(&c1[j], a);
}

// ---------- weight convert: LDS-tiled transpose, W1 rows scaled by sc[k] ----------
__global__ __launch_bounds__(256) void wt1_k(const float* __restrict__ W,
                                             const float* __restrict__ sc,
                                             u16* __restrict__ Bt) {
    __shared__ u16 t[64][68];
    int k0 = blockIdx.y * 64, c0 = blockIdx.x * 64;
    int tc = (threadIdx.x & 15) * 4;
    int tk = threadIdx.x >> 4;
#pragma unroll
    for (int i = 0; i < 64; i += 16) {
        float scr = sc[k0 + tk + i];
        float4 v = *(const float4*)(W + (size_t)(k0 + tk + i) * HCH + c0 + tc);
        t[tc + 0][tk + i] = f2bf(v.x * scr);
        t[tc + 1][tk + i] = f2bf(v.y * scr);
        t[tc + 2][tk + i] = f2bf(v.z * scr);
        t[tc + 3][tk + i] = f2bf(v.w * scr);
    }
    __syncthreads();
    int wk = (threadIdx.x & 15) * 4;
    int wc = threadIdx.x >> 4;
#pragma unroll
    for (int i = 0; i < 64; i += 16) {
        ushort4 o;
        o.x = t[wc + i][wk + 0]; o.y = t[wc + i][wk + 1];
        o.z = t[wc + i][wk + 2]; o.w = t[wc + i][wk + 3];
        *(ushort4*)(Bt + (size_t)(c0 + wc + i) * 1024 + k0 + wk) = o;
    }
}

__global__ __launch_bounds__(256) void wt2_k(const float* __restrict__ Wm,
                                             const float* __restrict__ Ws,
                                             u16* __restrict__ Bt) {
    __shared__ u16 t[64][68];
    int k0 = blockIdx.y * 64, c0 = blockIdx.x * 64;
    const float* W = (c0 < OUTCH) ? Wm : Ws;
    int cb = (c0 < OUTCH) ? c0 : c0 - OUTCH;
    int tc = (threadIdx.x & 15) * 4;
    int tk = threadIdx.x >> 4;
#pragma unroll
    for (int i = 0; i < 64; i += 16) {
        float4 v = *(const float4*)(W + (size_t)(k0 + tk + i) * OUTCH + cb + tc);
        t[tc + 0][tk + i] = f2bf(v.x);
        t[tc + 1][tk + i] = f2bf(v.y);
        t[tc + 2][tk + i] = f2bf(v.z);
        t[tc + 3][tk + i] = f2bf(v.w);
    }
    __syncthreads();
    int wk = (threadIdx.x & 15) * 4;
    int wc = threadIdx.x >> 4;
#pragma unroll
    for (int i = 0; i < 64; i += 16) {
        ushort4 o;
        o.x = t[wc + i][wk + 0]; o.y = t[wc + i][wk + 1];
        o.z = t[wc + i][wk + 2]; o.w = t[wc + i][wk + 3];
        *(ushort4*)(Bt + (size_t)(c0 + wc + i) * 1024 + k0 + wk) = o;
    }
}

// ---------- CSR build ----------
__global__ void deg_k(const int* __restrict__ dst, int* __restrict__ cnt) {
    int e = blockIdx.x * 256 + threadIdx.x;
    if (e < NEDGES) atomicAdd(&cnt[dst[e]], 1);
}
__global__ void dis_k(const int* __restrict__ cnt, float* __restrict__ dis,
                      float* __restrict__ rowsum) {
    int i = blockIdx.x * 256 + threadIdx.x;
    if (i < NNODES) {
        float d = rsqrtf((float)(cnt[i] + 1));
        dis[i] = d;
        rowsum[i] = d * d;        // self-loop weight; edge weights atomically added in fill_k
    }
}
__global__ void scan_k(const int* __restrict__ cnt, int* __restrict__ row_ptr,
                       int* __restrict__ cursor) {
    __shared__ int sm[256];
    int tid = threadIdx.x;
    const int per = 40;
    int base = tid * per;
    int s = 0;
    for (int i = 0; i < per; ++i) { int idx = base + i; if (idx < NNODES) s += cnt[idx]; }
    sm[tid] = s; __syncthreads();
    for (int off = 1; off < 256; off <<= 1) {
        int v = (tid >= off) ? sm[tid - off] : 0;
        __syncthreads();
        sm[tid] += v;
        __syncthreads();
    }
    int run = (tid == 0) ? 0 : sm[tid - 1];
    for (int i = 0; i < per; ++i) {
        int idx = base + i;
        if (idx < NNODES) { row_ptr[idx] = run; cursor[idx] = run; run += cnt[idx]; }
    }
    if (tid == 255) row_ptr[NNODES] = sm[255];
}
__global__ void fill_k(const int* __restrict__ src, const int* __restrict__ dst,
                       const float* __restrict__ dis, int* __restrict__ cursor,
                       int* __restrict__ csr_src, float* __restrict__ csr_w,
                       float* __restrict__ rowsum) {
    int e = blockIdx.x * 256 + threadIdx.x;
    if (e >= NEDGES) return;
    int s = src[e], d = dst[e];
    float w = dis[s] * dis[d];
    int pos = atomicAdd(&cursor[d], 1);
    csr_src[pos] = s;
    csr_w[pos] = w;
    atomicAdd(&rowsum[d], w);
}

// ---------- aggregation ----------
// MODE 1: += rowsum*c1 + b1, then leaky_relu
template<int MODE>
__global__ void agg_k(const u16* __restrict__ in, u16* __restrict__ out,
                      const int* __restrict__ row_ptr, const int* __restrict__ csr_src,
                      const float* __restrict__ csr_w, const float* __restrict__ dis,
                      const float* __restrict__ bias, const float* __restrict__ rowsum,
                      const float* __restrict__ c1) {
    int node = blockIdx.x;
    int c = threadIdx.x * 4;
    float dv = dis[node];
    float selfw = dv * dv;
    ushort4 sv = *(const ushort4*)(in + (size_t)node * HCH + c);
    float a0 = bf2f(sv.x) * selfw, a1 = bf2f(sv.y) * selfw;
    float a2 = bf2f(sv.z) * selfw, a3 = bf2f(sv.w) * selfw;
    int e0 = row_ptr[node], e1 = row_ptr[node + 1];
    for (int e = e0; e < e1; ++e) {
        int s = csr_src[e];
        float w = csr_w[e];
        ushort4 v = *(const ushort4*)(in + (size_t)s * HCH + c);
        a0 += bf2f(v.x) * w; a1 += bf2f(v.y) * w;
        a2 += bf2f(v.z) * w; a3 += bf2f(v.w) * w;
    }
    if (MODE == 1) {
        float rs = rowsum[node];
        float4 b = *(const float4*)(bias + c);
        float4 cc = *(const float4*)(c1 + c);
        a0 += rs * cc.x + b.x; a1 += rs * cc.y + b.y;
        a2 += rs * cc.z + b.z; a3 += rs * cc.w + b.w;
        a0 = a0 > 0.f ? a0 : NEG * a0;
        a1 = a1 > 0.f ? a1 : NEG * a1;
        a2 = a2 > 0.f ? a2 : NEG * a2;
        a3 = a3 > 0.f ? a3 : NEG * a3;
    }
    ushort4 o; o.x = f2bf(a0); o.y = f2bf(a1); o.z = f2bf(a2); o.w = f2bf(a3);
    *(ushort4*)(out + (size_t)node * HCH + c) = o;
}

// ---------- bf16 MFMA GEMM ----------
template<int EPI>
__global__ __launch_bounds__(256) void gemm_k(
    const u16* __restrict__ A, const u16* __restrict__ Bt,
    u16* __restrict__ Cbf, float* __restrict__ out,
    const float* __restrict__ bm, const float* __restrict__ bs) {
    __shared__ u16 As[128 * 32];
    __shared__ u16 Bs[128 * 32];
    const int tid = threadIdx.x;
    const int wave = tid >> 6;
    const int lane = tid & 63;
    const int row0 = blockIdx.y * 128;
    const int col0 = blockIdx.x * 128;
    const int wr = wave >> 1, wc = wave & 1;
    const int sr = lane >> 2;
    const int sc = (lane & 3) * 8;
    u16* AsW0 = &As[(wave * 16) * 32];
    u16* AsW1 = &As[(64 + wave * 16) * 32];
    u16* BsW0 = &Bs[(wave * 16) * 32];
    u16* BsW1 = &Bs[(64 + wave * 16) * 32];
    const u16* Ag0 = A + (size_t)(row0 + wave * 16 + sr) * 1024 + sc;
    const u16* Ag1 = A + (size_t)(row0 + 64 + wave * 16 + sr) * 1024 + sc;
    const u16* Bg0 = Bt + (size_t)(col0 + wave * 16 + sr) * 1024 + sc;
    const u16* Bg1 = Bt + (size_t)(col0 + 64 + wave * 16 + sr) * 1024 + sc;

    f32x4 acc[4][4] = {};
    const int arow = lane & 15;
    const int ak = (lane >> 4) * 8;
    for (int kk = 0; kk < 1024; kk += 32) {
        GL16(Ag0 + kk, AsW0);
        GL16(Ag1 + kk, AsW1);
        GL16(Bg0 + kk, BsW0);
        GL16(Bg1 + kk, BsW1);
        __syncthreads();
        bf16x8 af[4], bf[4];
#pragma unroll
        for (int m = 0; m < 4; ++m)
            af[m] = *reinterpret_cast<const bf16x8*>(&As[(wr * 64 + m * 16 + arow) * 32 + ak]);
#pragma unroll
        for (int n = 0; n < 4; ++n)
            bf[n] = *reinterpret_cast<const bf16x8*>(&Bs[(wc * 64 + n * 16 + arow) * 32 + ak]);
#pragma unroll
        for (int m = 0; m < 4; ++m)
#pragma unroll
            for (int n = 0; n < 4; ++n)
                acc[m][n] = __builtin_amdgcn_mfma_f32_16x16x32_bf16(af[m], bf[n], acc[m][n], 0, 0, 0);
        __syncthreads();
    }
    const int crow = (lane >> 4) * 4;
    const int ccol = lane & 15;
    if (EPI == 0) {
#pragma unroll
        for (int m = 0; m < 4; ++m) {
            int rbase = row0 + wr * 64 + m * 16 + crow;
#pragma unroll
            for (int n = 0; n < 4; ++n) {
                int col = col0 + wc * 64 + n * 16 + ccol;
                f32x4 v = acc[m][n];
#pragma unroll
                for (int r = 0; r < 4; ++r)
                    Cbf[(size_t)(rbase + r) * 1024 + col] = f2bf(v[r]);
            }
        }
    } else {
        const size_t NOUT = (size_t)NNODES * OUTCH;
#pragma unroll
        for (int n = 0; n < 4; ++n) {
            int col = col0 + wc * 64 + n * 16 + ccol;
            bool lo = col < OUTCH;
            int colo = lo ? col : col - OUTCH;
            float bias = lo ? bm[colo] : bs[colo];
#pragma unroll
            for (int m = 0; m < 4; ++m) {
                int rbase = row0 + wr * 64 + m * 16 + crow;
                f32x4 v = acc[m][n];
#pragma unroll
                for (int r = 0; r < 4; ++r) {
                    int rr = rbase + r;
                    if (rr < NNODES) {
                        float val = v[r] + bias;
                        if (lo) {
                            out[(size_t)rr * OUTCH + colo] = val;
                            out[NOUT + (size_t)rr * OUTCH + colo] = val;
                        } else {
                            out[2 * NOUT + (size_t)rr * OUTCH + colo] = val;
                        }
                    }
                }
            }
        }
    }
}

extern "C" void kernel_launch(void* const* d_in, const int* in_sizes, int n_in,
                              void* d_out, int out_size, void* d_ws, size_t ws_size,
                              hipStream_t stream) {
    const float* x   = (const float*)d_in[0];
    const int*   ei  = (const int*)d_in[1];
    const float* W1  = (const float*)d_in[2];
    const float* b1  = (const float*)d_in[3];
    const float* Wm  = (const float*)d_in[4];
    const float* bm  = (const float*)d_in[5];
    const float* Ws  = (const float*)d_in[6];
    const float* bs  = (const float*)d_in[7];
    const float* gw  = (const float*)d_in[8];
    const float* gb  = (const float*)d_in[9];
    const float* gms = (const float*)d_in[10];
    const int* srcI = ei;
    const int* dstI = ei + NEDGES;

    char* ws = (char*)d_ws;
    const size_t SBIG = (size_t)MPAD * 1024 * 2;
    u16* xn   = (u16*)(ws);
    u16* h1g  = (u16*)(ws + SBIG);
    u16* h    = (u16*)(ws + 2 * SBIG);
    u16* aggh = xn;                                 // xn dead after gemm1
    u16* Bt1  = (u16*)(ws + 3 * SBIG);
    u16* Bt2  = (u16*)(ws + 3 * SBIG + (size_t)2 * 1024 * 1024);
    char* small   = ws + 3 * SBIG + (size_t)4 * 1024 * 1024;
    // zeroed region: colsum | colsq | cnt | rowsum | c1
    float* colsum = (float*)(small);                 // 4096
    float* colsq  = (float*)(small + 4096);          // 4096
    int*   cnt    = (int*)(small + 8192);            // 40960
    float* rowsum = (float*)(small + 49152);         // 40960
    float* c1     = (float*)(small + 90112);         // 4096
    // non-zeroed:
    int*   row_ptr= (int*)(small + 94208);           // 40960
    int*   cursor = (int*)(small + 135168);          // 40960
    float* dis    = (float*)(small + 176128);        // 40960
    int*   csr_src= (int*)(small + 217088);          // 640000
    float* csr_w  = (float*)(small + 857088);        // 640000
    float* sc     = (float*)(small + 1497088);       // 4096
    float* sh     = (float*)(small + 1501184);       // 4096

    hipMemsetAsync(small, 0, 94208, stream);

    cast_k<<<10000, 256, 0, stream>>>(x, xn);                 // absorbs poison drain
    deg_k<<<625, 256, 0, stream>>>(dstI, cnt);
    dis_k<<<40, 256, 0, stream>>>(cnt, dis, rowsum);
    scan_k<<<1, 256, 0, stream>>>(cnt, row_ptr, cursor);
    fill_k<<<625, 256, 0, stream>>>(srcI, dstI, dis, cursor, csr_src, csr_w, rowsum);
    sumsq_k<<<625, 256, 0, stream>>>(xn, colsum, colsq);
    scale_k<<<4, 256, 0, stream>>>(colsum, colsq, gms, gw, gb, sc, sh);
    wt1_k<<<dim3(16, 16), 256, 0, stream>>>(W1, sc, Bt1);
    c1_k<<<dim3(4, 8), 256, 0, stream>>>(W1, sh, c1);
    wt2_k<<<dim3(16, 16), 256, 0, stream>>>(Wm, Ws, Bt2);

    gemm_k<0><<<dim3(8, 79), 256, 0, stream>>>(xn, Bt1, h1g, nullptr, nullptr, nullptr);
    agg_k<1><<<NNODES, 256, 0, stream>>>(h1g, h, row_ptr, csr_src, csr_w, dis, b1, rowsum, c1);
    agg_k<0><<<NNODES, 256, 0, stream>>>(h, aggh, row_ptr, csr_src, csr_w, dis, nullptr, nullptr, nullptr);
    gemm_k<1><<<dim3(8, 79), 256, 0, stream>>>(aggh, Bt2, nullptr, (float*)d_out, bm, bs);
}

// Round 4
// 427.948 us; speedup vs baseline: 1.0150x; 1.0150x over previous
//
#include <hip/hip_runtime.h>
#include <hip/hip_bf16.h>
#include <stdint.h>

#define NNODES 10000
#define NEDGES 160000
#define INCH 1024
#define HCH 1024
#define OUTCH 512
#define MPAD 10112           // 79 * 128
#define EPSV 1e-5f
#define NEG 0.1f
#define NSB 625              // stat blocks

typedef unsigned short u16;
typedef __bf16 bf16x8 __attribute__((ext_vector_type(8)));
typedef float f32x4 __attribute__((ext_vector_type(4)));
typedef __attribute__((address_space(1))) unsigned int gu32;
typedef __attribute__((address_space(3))) unsigned int lu32;

#define GL16(g, l) __builtin_amdgcn_global_load_lds((const gu32*)(g), (lu32*)(l), 16, 0, 0)

__device__ __forceinline__ float bf2f(u16 u) {
    union { unsigned int i; float f; } v; v.i = ((unsigned int)u) << 16; return v.f;
}
__device__ __forceinline__ u16 f2bf(float f) {
    union { float f; unsigned int i; } v; v.f = f;
    unsigned int r = v.i + 0x7fffu + ((v.i >> 16) & 1u);
    return (u16)(r >> 16);
}

// ---------- fused cast fp32->bf16 + per-block column stats (NO atomics) ----------
// 625 blocks x 16 rows. Thread t owns columns 4t..4t+3.
__global__ __launch_bounds__(256) void cast_stats_k(const float* __restrict__ x,
                                                    u16* __restrict__ xn,
                                                    float* __restrict__ psum,
                                                    float* __restrict__ psq) {
    int c = threadIdx.x * 4;
    int r0 = blockIdx.x * 16;
    float s0 = 0.f, s1 = 0.f, s2 = 0.f, s3 = 0.f;
    float q0 = 0.f, q1 = 0.f, q2 = 0.f, q3 = 0.f;
#pragma unroll
    for (int r = 0; r < 16; ++r) {
        size_t off = (size_t)(r0 + r) * INCH + c;
        float4 v = *(const float4*)(x + off);
        ushort4 o;
        o.x = f2bf(v.x); o.y = f2bf(v.y); o.z = f2bf(v.z); o.w = f2bf(v.w);
        *(ushort4*)(xn + off) = o;
        float f0 = bf2f(o.x), f1 = bf2f(o.y), f2 = bf2f(o.z), f3 = bf2f(o.w);
        s0 += f0; s1 += f1; s2 += f2; s3 += f3;
        q0 += f0 * f0; q1 += f1 * f1; q2 += f2 * f2; q3 += f3 * f3;
    }
    size_t pb = (size_t)blockIdx.x * 1024 + c;
    *(float4*)(psum + pb) = make_float4(s0, s1, s2, s3);
    *(float4*)(psq + pb)  = make_float4(q0, q1, q2, q3);
}

// ---------- reduce partials -> per-column scale/shift ----------
// var = E[x^2] - g*(2-g)*mean^2 ; sc = rsqrt(var+eps)*w ; sh = b - g*mean*sc
__global__ __launch_bounds__(256) void scale2_k(const float* __restrict__ psum,
                                                const float* __restrict__ psq,
                                                const float* __restrict__ gms,
                                                const float* __restrict__ gw,
                                                const float* __restrict__ gb,
                                                float* __restrict__ sc, float* __restrict__ sh) {
    int c = blockIdx.x * 256 + threadIdx.x;   // 0..1023
    float s = 0.f, q = 0.f;
    for (int b = 0; b < NSB; ++b) {
        s += psum[(size_t)b * 1024 + c];
        q += psq[(size_t)b * 1024 + c];
    }
    const float invn = 1.0f / NNODES;
    float m = s * invn;
    float msq = q * invn;
    float g = gms[c];
    float var = msq - g * (2.0f - g) * m * m;
    float scale = rsqrtf(var + EPSV) * gw[c];
    sc[c] = scale;
    sh[c] = gb[c] - g * m * scale;
}

// ---------- rank-1 correction vector: c1[j] = sum_k sh[k] * W1[k,j] ----------
__global__ void c1_k(const float* __restrict__ W1, const float* __restrict__ sh,
                     float* __restrict__ c1) {
    int j = blockIdx.x * 256 + threadIdx.x;
    int k0 = blockIdx.y * 128;
    float a = 0.f;
#pragma unroll 4
    for (int k = k0; k < k0 + 128; ++k) a += sh[k] * W1[(size_t)k * HCH + j];
    atomicAdd(&c1[j], a);
}

// ---------- weight convert: LDS-tiled transpose, W1 rows scaled by sc[k] ----------
__global__ __launch_bounds__(256) void wt1_k(const float* __restrict__ W,
                                             const float* __restrict__ sc,
                                             u16* __restrict__ Bt) {
    __shared__ u16 t[64][68];
    int k0 = blockIdx.y * 64, c0 = blockIdx.x * 64;
    int tc = (threadIdx.x & 15) * 4;
    int tk = threadIdx.x >> 4;
#pragma unroll
    for (int i = 0; i < 64; i += 16) {
        float scr = sc[k0 + tk + i];
        float4 v = *(const float4*)(W + (size_t)(k0 + tk + i) * HCH + c0 + tc);
        t[tc + 0][tk + i] = f2bf(v.x * scr);
        t[tc + 1][tk + i] = f2bf(v.y * scr);
        t[tc + 2][tk + i] = f2bf(v.z * scr);
        t[tc + 3][tk + i] = f2bf(v.w * scr);
    }
    __syncthreads();
    int wk = (threadIdx.x & 15) * 4;
    int wc = threadIdx.x >> 4;
#pragma unroll
    for (int i = 0; i < 64; i += 16) {
        ushort4 o;
        o.x = t[wc + i][wk + 0]; o.y = t[wc + i][wk + 1];
        o.z = t[wc + i][wk + 2]; o.w = t[wc + i][wk + 3];
        *(ushort4*)(Bt + (size_t)(c0 + wc + i) * 1024 + k0 + wk) = o;
    }
}

__global__ __launch_bounds__(256) void wt2_k(const float* __restrict__ Wm,
                                             const float* __restrict__ Ws,
                                             u16* __restrict__ Bt) {
    __shared__ u16 t[64][68];
    int k0 = blockIdx.y * 64, c0 = blockIdx.x * 64;
    const float* W = (c0 < OUTCH) ? Wm : Ws;
    int cb = (c0 < OUTCH) ? c0 : c0 - OUTCH;
    int tc = (threadIdx.x & 15) * 4;
    int tk = threadIdx.x >> 4;
#pragma unroll
    for (int i = 0; i < 64; i += 16) {
        float4 v = *(const float4*)(W + (size_t)(k0 + tk + i) * OUTCH + cb + tc);
        t[tc + 0][tk + i] = f2bf(v.x);
        t[tc + 1][tk + i] = f2bf(v.y);
        t[tc + 2][tk + i] = f2bf(v.z);
        t[tc + 3][tk + i] = f2bf(v.w);
    }
    __syncthreads();
    int wk = (threadIdx.x & 15) * 4;
    int wc = threadIdx.x >> 4;
#pragma unroll
    for (int i = 0; i < 64; i += 16) {
        ushort4 o;
        o.x = t[wc + i][wk + 0]; o.y = t[wc + i][wk + 1];
        o.z = t[wc + i][wk + 2]; o.w = t[wc + i][wk + 3];
        *(ushort4*)(Bt + (size_t)(c0 + wc + i) * 1024 + k0 + wk) = o;
    }
}

// ---------- CSR build ----------
__global__ void deg_k(const int* __restrict__ dst, int* __restrict__ cnt) {
    int e = blockIdx.x * 256 + threadIdx.x;
    if (e < NEDGES) atomicAdd(&cnt[dst[e]], 1);
}
__global__ void dis_k(const int* __restrict__ cnt, float* __restrict__ dis,
                      float* __restrict__ rowsum) {
    int i = blockIdx.x * 256 + threadIdx.x;
    if (i < NNODES) {
        float d = rsqrtf((float)(cnt[i] + 1));
        dis[i] = d;
        rowsum[i] = d * d;
    }
}
__global__ void scan_k(const int* __restrict__ cnt, int* __restrict__ row_ptr,
                       int* __restrict__ cursor) {
    __shared__ int sm[256];
    int tid = threadIdx.x;
    const int per = 40;
    int base = tid * per;
    int s = 0;
    for (int i = 0; i < per; ++i) { int idx = base + i; if (idx < NNODES) s += cnt[idx]; }
    sm[tid] = s; __syncthreads();
    for (int off = 1; off < 256; off <<= 1) {
        int v = (tid >= off) ? sm[tid - off] : 0;
        __syncthreads();
        sm[tid] += v;
        __syncthreads();
    }
    int run = (tid == 0) ? 0 : sm[tid - 1];
    for (int i = 0; i < per; ++i) {
        int idx = base + i;
        if (idx < NNODES) { row_ptr[idx] = run; cursor[idx] = run; run += cnt[idx]; }
    }
    if (tid == 255) row_ptr[NNODES] = sm[255];
}
__global__ void fill_k(const int* __restrict__ src, const int* __restrict__ dst,
                       const float* __restrict__ dis, int* __restrict__ cursor,
                       int* __restrict__ csr_src, float* __restrict__ csr_w,
                       float* __restrict__ rowsum) {
    int e = blockIdx.x * 256 + threadIdx.x;
    if (e >= NEDGES) return;
    int s = src[e], d = dst[e];
    float w = dis[s] * dis[d];
    int pos = atomicAdd(&cursor[d], 1);
    csr_src[pos] = s;
    csr_w[pos] = w;
    atomicAdd(&rowsum[d], w);
}

// ---------- aggregation ----------
// MODE 1: += rowsum*c1 + b1, then leaky_relu
template<int MODE>
__global__ void agg_k(const u16* __restrict__ in, u16* __restrict__ out,
                      const int* __restrict__ row_ptr, const int* __restrict__ csr_src,
                      const float* __restrict__ csr_w, const float* __restrict__ dis,
                      const float* __restrict__ bias, const float* __restrict__ rowsum,
                      const float* __restrict__ c1) {
    int node = blockIdx.x;
    int c = threadIdx.x * 4;
    float dv = dis[node];
    float selfw = dv * dv;
    ushort4 sv = *(const ushort4*)(in + (size_t)node * HCH + c);
    float a0 = bf2f(sv.x) * selfw, a1 = bf2f(sv.y) * selfw;
    float a2 = bf2f(sv.z) * selfw, a3 = bf2f(sv.w) * selfw;
    int e0 = row_ptr[node], e1 = row_ptr[node + 1];
    for (int e = e0; e < e1; ++e) {
        int s = csr_src[e];
        float w = csr_w[e];
        ushort4 v = *(const ushort4*)(in + (size_t)s * HCH + c);
        a0 += bf2f(v.x) * w; a1 += bf2f(v.y) * w;
        a2 += bf2f(v.z) * w; a3 += bf2f(v.w) * w;
    }
    if (MODE == 1) {
        float rs = rowsum[node];
        float4 b = *(const float4*)(bias + c);
        float4 cc = *(const float4*)(c1 + c);
        a0 += rs * cc.x + b.x; a1 += rs * cc.y + b.y;
        a2 += rs * cc.z + b.z; a3 += rs * cc.w + b.w;
        a0 = a0 > 0.f ? a0 : NEG * a0;
        a1 = a1 > 0.f ? a1 : NEG * a1;
        a2 = a2 > 0.f ? a2 : NEG * a2;
        a3 = a3 > 0.f ? a3 : NEG * a3;
    }
    ushort4 o; o.x = f2bf(a0); o.y = f2bf(a1); o.z = f2bf(a2); o.w = f2bf(a3);
    *(ushort4*)(out + (size_t)node * HCH + c) = o;
}

// ---------- bf16 MFMA GEMM ----------
template<int EPI>
__global__ __launch_bounds__(256) void gemm_k(
    const u16* __restrict__ A, const u16* __restrict__ Bt,
    u16* __restrict__ Cbf, float* __restrict__ out,
    const float* __restrict__ bm, const float* __restrict__ bs) {
    __shared__ u16 As[128 * 32];
    __shared__ u16 Bs[128 * 32];
    const int tid = threadIdx.x;
    const int wave = tid >> 6;
    const int lane = tid & 63;
    const int row0 = blockIdx.y * 128;
    const int col0 = blockIdx.x * 128;
    const int wr = wave >> 1, wc = wave & 1;
    const int sr = lane >> 2;
    const int sc = (lane & 3) * 8;
    u16* AsW0 = &As[(wave * 16) * 32];
    u16* AsW1 = &As[(64 + wave * 16) * 32];
    u16* BsW0 = &Bs[(wave * 16) * 32];
    u16* BsW1 = &Bs[(64 + wave * 16) * 32];
    const u16* Ag0 = A + (size_t)(row0 + wave * 16 + sr) * 1024 + sc;
    const u16* Ag1 = A + (size_t)(row0 + 64 + wave * 16 + sr) * 1024 + sc;
    const u16* Bg0 = Bt + (size_t)(col0 + wave * 16 + sr) * 1024 + sc;
    const u16* Bg1 = Bt + (size_t)(col0 + 64 + wave * 16 + sr) * 1024 + sc;

    f32x4 acc[4][4] = {};
    const int arow = lane & 15;
    const int ak = (lane >> 4) * 8;
    for (int kk = 0; kk < 1024; kk += 32) {
        GL16(Ag0 + kk, AsW0);
        GL16(Ag1 + kk, AsW1);
        GL16(Bg0 + kk, BsW0);
        GL16(Bg1 + kk, BsW1);
        __syncthreads();
        bf16x8 af[4], bf[4];
#pragma unroll
        for (int m = 0; m < 4; ++m)
            af[m] = *reinterpret_cast<const bf16x8*>(&As[(wr * 64 + m * 16 + arow) * 32 + ak]);
#pragma unroll
        for (int n = 0; n < 4; ++n)
            bf[n] = *reinterpret_cast<const bf16x8*>(&Bs[(wc * 64 + n * 16 + arow) * 32 + ak]);
#pragma unroll
        for (int m = 0; m < 4; ++m)
#pragma unroll
            for (int n = 0; n < 4; ++n)
                acc[m][n] = __builtin_amdgcn_mfma_f32_16x16x32_bf16(af[m], bf[n], acc[m][n], 0, 0, 0);
        __syncthreads();
    }
    const int crow = (lane >> 4) * 4;
    const int ccol = lane & 15;
    if (EPI == 0) {
#pragma unroll
        for (int m = 0; m < 4; ++m) {
            int rbase = row0 + wr * 64 + m * 16 + crow;
#pragma unroll
            for (int n = 0; n < 4; ++n) {
                int col = col0 + wc * 64 + n * 16 + ccol;
                f32x4 v = acc[m][n];
#pragma unroll
                for (int r = 0; r < 4; ++r)
                    Cbf[(size_t)(rbase + r) * 1024 + col] = f2bf(v[r]);
            }
        }
    } else {
        const size_t NOUT = (size_t)NNODES * OUTCH;
#pragma unroll
        for (int n = 0; n < 4; ++n) {
            int col = col0 + wc * 64 + n * 16 + ccol;
            bool lo = col < OUTCH;
            int colo = lo ? col : col - OUTCH;
            float bias = lo ? bm[colo] : bs[colo];
#pragma unroll
            for (int m = 0; m < 4; ++m) {
                int rbase = row0 + wr * 64 + m * 16 + crow;
                f32x4 v = acc[m][n];
#pragma unroll
                for (int r = 0; r < 4; ++r) {
                    int rr = rbase + r;
                    if (rr < NNODES) {
                        float val = v[r] + bias;
                        if (lo) {
                            out[(size_t)rr * OUTCH + colo] = val;
                            out[NOUT + (size_t)rr * OUTCH + colo] = val;
                        } else {
                            out[2 * NOUT + (size_t)rr * OUTCH + colo] = val;
                        }
                    }
                }
            }
        }
    }
}

extern "C" void kernel_launch(void* const* d_in, const int* in_sizes, int n_in,
                              void* d_out, int out_size, void* d_ws, size_t ws_size,
                              hipStream_t stream) {
    const float* x   = (const float*)d_in[0];
    const int*   ei  = (const int*)d_in[1];
    const float* W1  = (const float*)d_in[2];
    const float* b1  = (const float*)d_in[3];
    const float* Wm  = (const float*)d_in[4];
    const float* bm  = (const float*)d_in[5];
    const float* Ws  = (const float*)d_in[6];
    const float* bs  = (const float*)d_in[7];
    const float* gw  = (const float*)d_in[8];
    const float* gb  = (const float*)d_in[9];
    const float* gms = (const float*)d_in[10];
    const int* srcI = ei;
    const int* dstI = ei + NEDGES;

    char* ws = (char*)d_ws;
    const size_t SBIG = (size_t)MPAD * 1024 * 2;
    u16* xn   = (u16*)(ws);
    u16* h1g  = (u16*)(ws + SBIG);
    u16* h    = (u16*)(ws + 2 * SBIG);
    u16* aggh = xn;                                 // xn dead after gemm1
    u16* Bt1  = (u16*)(ws + 3 * SBIG);
    u16* Bt2  = (u16*)(ws + 3 * SBIG + (size_t)2 * 1024 * 1024);
    // partial stats live inside h1g's buffer (dead until gemm1, consumed before)
    float* psum = (float*)(ws + SBIG);                        // 625*1024*4 = 2.56 MB
    float* psq  = (float*)(ws + SBIG + (size_t)NSB * 4096);   // 2.56 MB  (total 5.12 < 20.7 MB)
    char* small   = ws + 3 * SBIG + (size_t)4 * 1024 * 1024;
    // zeroed region: cnt | rowsum | c1
    int*   cnt    = (int*)(small);                   // 40960
    float* rowsum = (float*)(small + 40960);         // 40960
    float* c1     = (float*)(small + 81920);         // 4096
    // non-zeroed:
    int*   row_ptr= (int*)(small + 86016);           // 40960
    int*   cursor = (int*)(small + 126976);          // 40960
    float* dis    = (float*)(small + 167936);        // 40960
    int*   csr_src= (int*)(small + 208896);          // 640000
    float* csr_w  = (float*)(small + 848896);        // 640000
    float* sc     = (float*)(small + 1488896);       // 4096
    float* sh     = (float*)(small + 1492992);       // 4096

    hipMemsetAsync(small, 0, 86016, stream);

    cast_stats_k<<<NSB, 256, 0, stream>>>(x, xn, psum, psq);  // absorbs poison drain
    deg_k<<<625, 256, 0, stream>>>(dstI, cnt);
    dis_k<<<40, 256, 0, stream>>>(cnt, dis, rowsum);
    scan_k<<<1, 256, 0, stream>>>(cnt, row_ptr, cursor);
    fill_k<<<625, 256, 0, stream>>>(srcI, dstI, dis, cursor, csr_src, csr_w, rowsum);
    scale2_k<<<4, 256, 0, stream>>>(psum, psq, gms, gw, gb, sc, sh);
    wt1_k<<<dim3(16, 16), 256, 0, stream>>>(W1, sc, Bt1);
    c1_k<<<dim3(4, 8), 256, 0, stream>>>(W1, sh, c1);
    wt2_k<<<dim3(16, 16), 256, 0, stream>>>(Wm, Ws, Bt2);

    gemm_k<0><<<dim3(8, 79), 256, 0, stream>>>(xn, Bt1, h1g, nullptr, nullptr, nullptr);
    agg_k<1><<<NNODES, 256, 0, stream>>>(h1g, h, row_ptr, csr_src, csr_w, dis, b1, rowsum, c1);
    agg_k<0><<<NNODES, 256, 0, stream>>>(h, aggh, row_ptr, csr_src, csr_w, dis, nullptr, nullptr, nullptr);
    gemm_k<1><<<dim3(8, 79), 256, 0, stream>>>(aggh, Bt2, nullptr, (float*)d_out, bm, bs);
}

// Round 5
// 383.358 us; speedup vs baseline: 1.1331x; 1.1163x over previous
//
#include <hip/hip_runtime.h>
#include <hip/hip_bf16.h>
#include <stdint.h>

#define NNODES 10000
#define NEDGES 160000
#define INCH 1024
#define HCH 1024
#define OUTCH 512
#define MPAD 10112           // 79 * 128
#define EPSV 1e-5f
#define NEG 0.1f
#define NSB 625              // stat blocks
#define NSB2 32              // second-level stat blocks

typedef unsigned short u16;
typedef __bf16 bf16x8 __attribute__((ext_vector_type(8)));
typedef float f32x4 __attribute__((ext_vector_type(4)));
typedef __attribute__((address_space(1))) unsigned int gu32;
typedef __attribute__((address_space(3))) unsigned int lu32;

#define GL16(g, l) __builtin_amdgcn_global_load_lds((const gu32*)(g), (lu32*)(l), 16, 0, 0)

__device__ __forceinline__ float bf2f(u16 u) {
    union { unsigned int i; float f; } v; v.i = ((unsigned int)u) << 16; return v.f;
}
__device__ __forceinline__ u16 f2bf(float f) {
    union { float f; unsigned int i; } v; v.f = f;
    unsigned int r = v.i + 0x7fffu + ((v.i >> 16) & 1u);
    return (u16)(r >> 16);
}

// ---------- fused cast fp32->bf16 + per-block column stats (NO atomics) ----------
__global__ __launch_bounds__(256) void cast_stats_k(const float* __restrict__ x,
                                                    u16* __restrict__ xn,
                                                    float* __restrict__ psum,
                                                    float* __restrict__ psq) {
    int c = threadIdx.x * 4;
    int r0 = blockIdx.x * 16;
    float s0 = 0.f, s1 = 0.f, s2 = 0.f, s3 = 0.f;
    float q0 = 0.f, q1 = 0.f, q2 = 0.f, q3 = 0.f;
#pragma unroll
    for (int r = 0; r < 16; ++r) {
        size_t off = (size_t)(r0 + r) * INCH + c;
        float4 v = *(const float4*)(x + off);
        ushort4 o;
        o.x = f2bf(v.x); o.y = f2bf(v.y); o.z = f2bf(v.z); o.w = f2bf(v.w);
        *(ushort4*)(xn + off) = o;
        float f0 = bf2f(o.x), f1 = bf2f(o.y), f2 = bf2f(o.z), f3 = bf2f(o.w);
        s0 += f0; s1 += f1; s2 += f2; s3 += f3;
        q0 += f0 * f0; q1 += f1 * f1; q2 += f2 * f2; q3 += f3 * f3;
    }
    size_t pb = (size_t)blockIdx.x * 1024 + c;
    *(float4*)(psum + pb) = make_float4(s0, s1, s2, s3);
    *(float4*)(psq + pb)  = make_float4(q0, q1, q2, q3);
}

// ---------- stage-1 reduce: 625 partials -> 32 partials ----------
__global__ __launch_bounds__(256) void reduce1_k(const float* __restrict__ psum,
                                                 const float* __restrict__ psq,
                                                 float* __restrict__ psum2,
                                                 float* __restrict__ psq2) {
    int c = threadIdx.x * 4;
    int b0 = blockIdx.x * 20;
    int b1 = min(b0 + 20, NSB);
    f32x4 s = {0.f, 0.f, 0.f, 0.f}, q = {0.f, 0.f, 0.f, 0.f};
    for (int b = b0; b < b1; ++b) {
        f32x4 vs = *(const f32x4*)(psum + (size_t)b * 1024 + c);
        f32x4 vq = *(const f32x4*)(psq + (size_t)b * 1024 + c);
        s += vs; q += vq;
    }
    *(f32x4*)(psum2 + (size_t)blockIdx.x * 1024 + c) = s;
    *(f32x4*)(psq2 + (size_t)blockIdx.x * 1024 + c) = q;
}

// ---------- stage-2: reduce 32 partials -> per-column scale/shift ----------
// var = E[x^2] - g*(2-g)*mean^2 ; sc = rsqrt(var+eps)*w ; sh = b - g*mean*sc
__global__ __launch_bounds__(256) void scale2_k(const float* __restrict__ psum2,
                                                const float* __restrict__ psq2,
                                                const float* __restrict__ gms,
                                                const float* __restrict__ gw,
                                                const float* __restrict__ gb,
                                                float* __restrict__ sc, float* __restrict__ sh) {
    int c = blockIdx.x * 256 + threadIdx.x;   // 0..1023
    float s = 0.f, q = 0.f;
#pragma unroll
    for (int b = 0; b < NSB2; ++b) {
        s += psum2[(size_t)b * 1024 + c];
        q += psq2[(size_t)b * 1024 + c];
    }
    const float invn = 1.0f / NNODES;
    float m = s * invn;
    float msq = q * invn;
    float g = gms[c];
    float var = msq - g * (2.0f - g) * m * m;
    float scale = rsqrtf(var + EPSV) * gw[c];
    sc[c] = scale;
    sh[c] = gb[c] - g * m * scale;
}

// ---------- rank-1 correction vector: c1[j] = sum_k sh[k] * W1[k,j] ----------
__global__ void c1_k(const float* __restrict__ W1, const float* __restrict__ sh,
                     float* __restrict__ c1) {
    int j = blockIdx.x * 256 + threadIdx.x;
    int k0 = blockIdx.y * 128;
    float a = 0.f;
#pragma unroll 4
    for (int k = k0; k < k0 + 128; ++k) a += sh[k] * W1[(size_t)k * HCH + j];
    atomicAdd(&c1[j], a);
}

// ---------- weight convert: LDS-tiled transpose, W1 rows scaled by sc[k] ----------
__global__ __launch_bounds__(256) void wt1_k(const float* __restrict__ W,
                                             const float* __restrict__ sc,
                                             u16* __restrict__ Bt) {
    __shared__ u16 t[64][68];
    int k0 = blockIdx.y * 64, c0 = blockIdx.x * 64;
    int tc = (threadIdx.x & 15) * 4;
    int tk = threadIdx.x >> 4;
#pragma unroll
    for (int i = 0; i < 64; i += 16) {
        float scr = sc[k0 + tk + i];
        float4 v = *(const float4*)(W + (size_t)(k0 + tk + i) * HCH + c0 + tc);
        t[tc + 0][tk + i] = f2bf(v.x * scr);
        t[tc + 1][tk + i] = f2bf(v.y * scr);
        t[tc + 2][tk + i] = f2bf(v.z * scr);
        t[tc + 3][tk + i] = f2bf(v.w * scr);
    }
    __syncthreads();
    int wk = (threadIdx.x & 15) * 4;
    int wc = threadIdx.x >> 4;
#pragma unroll
    for (int i = 0; i < 64; i += 16) {
        ushort4 o;
        o.x = t[wc + i][wk + 0]; o.y = t[wc + i][wk + 1];
        o.z = t[wc + i][wk + 2]; o.w = t[wc + i][wk + 3];
        *(ushort4*)(Bt + (size_t)(c0 + wc + i) * 1024 + k0 + wk) = o;
    }
}

__global__ __launch_bounds__(256) void wt2_k(const float* __restrict__ Wm,
                                             const float* __restrict__ Ws,
                                             u16* __restrict__ Bt) {
    __shared__ u16 t[64][68];
    int k0 = blockIdx.y * 64, c0 = blockIdx.x * 64;
    const float* W = (c0 < OUTCH) ? Wm : Ws;
    int cb = (c0 < OUTCH) ? c0 : c0 - OUTCH;
    int tc = (threadIdx.x & 15) * 4;
    int tk = threadIdx.x >> 4;
#pragma unroll
    for (int i = 0; i < 64; i += 16) {
        float4 v = *(const float4*)(W + (size_t)(k0 + tk + i) * OUTCH + cb + tc);
        t[tc + 0][tk + i] = f2bf(v.x);
        t[tc + 1][tk + i] = f2bf(v.y);
        t[tc + 2][tk + i] = f2bf(v.z);
        t[tc + 3][tk + i] = f2bf(v.w);
    }
    __syncthreads();
    int wk = (threadIdx.x & 15) * 4;
    int wc = threadIdx.x >> 4;
#pragma unroll
    for (int i = 0; i < 64; i += 16) {
        ushort4 o;
        o.x = t[wc + i][wk + 0]; o.y = t[wc + i][wk + 1];
        o.z = t[wc + i][wk + 2]; o.w = t[wc + i][wk + 3];
        *(ushort4*)(Bt + (size_t)(c0 + wc + i) * 1024 + k0 + wk) = o;
    }
}

// ---------- CSR build ----------
__global__ void deg_k(const int* __restrict__ dst, int* __restrict__ cnt) {
    int e = blockIdx.x * 256 + threadIdx.x;
    if (e < NEDGES) atomicAdd(&cnt[dst[e]], 1);
}
__global__ void dis_k(const int* __restrict__ cnt, float* __restrict__ dis,
                      float* __restrict__ rowsum) {
    int i = blockIdx.x * 256 + threadIdx.x;
    if (i < NNODES) {
        float d = rsqrtf((float)(cnt[i] + 1));
        dis[i] = d;
        rowsum[i] = d * d;
    }
}
__global__ void scan_k(const int* __restrict__ cnt, int* __restrict__ row_ptr,
                       int* __restrict__ cursor) {
    __shared__ int sm[256];
    int tid = threadIdx.x;
    const int per = 40;
    int base = tid * per;
    int s = 0;
    for (int i = 0; i < per; ++i) { int idx = base + i; if (idx < NNODES) s += cnt[idx]; }
    sm[tid] = s; __syncthreads();
    for (int off = 1; off < 256; off <<= 1) {
        int v = (tid >= off) ? sm[tid - off] : 0;
        __syncthreads();
        sm[tid] += v;
        __syncthreads();
    }
    int run = (tid == 0) ? 0 : sm[tid - 1];
    for (int i = 0; i < per; ++i) {
        int idx = base + i;
        if (idx < NNODES) { row_ptr[idx] = run; cursor[idx] = run; run += cnt[idx]; }
    }
    if (tid == 255) row_ptr[NNODES] = sm[255];
}
__global__ void fill_k(const int* __restrict__ src, const int* __restrict__ dst,
                       const float* __restrict__ dis, int* __restrict__ cursor,
                       int* __restrict__ csr_src, float* __restrict__ csr_w,
                       float* __restrict__ rowsum) {
    int e = blockIdx.x * 256 + threadIdx.x;
    if (e >= NEDGES) return;
    int s = src[e], d = dst[e];
    float w = dis[s] * dis[d];
    int pos = atomicAdd(&cursor[d], 1);
    csr_src[pos] = s;
    csr_w[pos] = w;
    atomicAdd(&rowsum[d], w);
}

// ---------- aggregation ----------
// MODE 1: += rowsum*c1 + b1, then leaky_relu
template<int MODE>
__global__ void agg_k(const u16* __restrict__ in, u16* __restrict__ out,
                      const int* __restrict__ row_ptr, const int* __restrict__ csr_src,
                      const float* __restrict__ csr_w, const float* __restrict__ dis,
                      const float* __restrict__ bias, const float* __restrict__ rowsum,
                      const float* __restrict__ c1) {
    int node = blockIdx.x;
    int c = threadIdx.x * 4;
    float dv = dis[node];
    float selfw = dv * dv;
    ushort4 sv = *(const ushort4*)(in + (size_t)node * HCH + c);
    float a0 = bf2f(sv.x) * selfw, a1 = bf2f(sv.y) * selfw;
    float a2 = bf2f(sv.z) * selfw, a3 = bf2f(sv.w) * selfw;
    int e0 = row_ptr[node], e1 = row_ptr[node + 1];
    for (int e = e0; e < e1; ++e) {
        int s = csr_src[e];
        float w = csr_w[e];
        ushort4 v = *(const ushort4*)(in + (size_t)s * HCH + c);
        a0 += bf2f(v.x) * w; a1 += bf2f(v.y) * w;
        a2 += bf2f(v.z) * w; a3 += bf2f(v.w) * w;
    }
    if (MODE == 1) {
        float rs = rowsum[node];
        float4 b = *(const float4*)(bias + c);
        float4 cc = *(const float4*)(c1 + c);
        a0 += rs * cc.x + b.x; a1 += rs * cc.y + b.y;
        a2 += rs * cc.z + b.z; a3 += rs * cc.w + b.w;
        a0 = a0 > 0.f ? a0 : NEG * a0;
        a1 = a1 > 0.f ? a1 : NEG * a1;
        a2 = a2 > 0.f ? a2 : NEG * a2;
        a3 = a3 > 0.f ? a3 : NEG * a3;
    }
    ushort4 o; o.x = f2bf(a0); o.y = f2bf(a1); o.z = f2bf(a2); o.w = f2bf(a3);
    *(ushort4*)(out + (size_t)node * HCH + c) = o;
}

// ---------- bf16 MFMA GEMM ----------
template<int EPI>
__global__ __launch_bounds__(256) void gemm_k(
    const u16* __restrict__ A, const u16* __restrict__ Bt,
    u16* __restrict__ Cbf, float* __restrict__ out,
    const float* __restrict__ bm, const float* __restrict__ bs) {
    __shared__ u16 As[128 * 32];
    __shared__ u16 Bs[128 * 32];
    const int tid = threadIdx.x;
    const int wave = tid >> 6;
    const int lane = tid & 63;
    const int row0 = blockIdx.y * 128;
    const int col0 = blockIdx.x * 128;
    const int wr = wave >> 1, wc = wave & 1;
    const int sr = lane >> 2;
    const int sc = (lane & 3) * 8;
    u16* AsW0 = &As[(wave * 16) * 32];
    u16* AsW1 = &As[(64 + wave * 16) * 32];
    u16* BsW0 = &Bs[(wave * 16) * 32];
    u16* BsW1 = &Bs[(64 + wave * 16) * 32];
    const u16* Ag0 = A + (size_t)(row0 + wave * 16 + sr) * 1024 + sc;
    const u16* Ag1 = A + (size_t)(row0 + 64 + wave * 16 + sr) * 1024 + sc;
    const u16* Bg0 = Bt + (size_t)(col0 + wave * 16 + sr) * 1024 + sc;
    const u16* Bg1 = Bt + (size_t)(col0 + 64 + wave * 16 + sr) * 1024 + sc;

    f32x4 acc[4][4] = {};
    const int arow = lane & 15;
    const int ak = (lane >> 4) * 8;
    for (int kk = 0; kk < 1024; kk += 32) {
        GL16(Ag0 + kk, AsW0);
        GL16(Ag1 + kk, AsW1);
        GL16(Bg0 + kk, BsW0);
        GL16(Bg1 + kk, BsW1);
        __syncthreads();
        bf16x8 af[4], bf[4];
#pragma unroll
        for (int m = 0; m < 4; ++m)
            af[m] = *reinterpret_cast<const bf16x8*>(&As[(wr * 64 + m * 16 + arow) * 32 + ak]);
#pragma unroll
        for (int n = 0; n < 4; ++n)
            bf[n] = *reinterpret_cast<const bf16x8*>(&Bs[(wc * 64 + n * 16 + arow) * 32 + ak]);
#pragma unroll
        for (int m = 0; m < 4; ++m)
#pragma unroll
            for (int n = 0; n < 4; ++n)
                acc[m][n] = __builtin_amdgcn_mfma_f32_16x16x32_bf16(af[m], bf[n], acc[m][n], 0, 0, 0);
        __syncthreads();
    }
    const int crow = (lane >> 4) * 4;
    const int ccol = lane & 15;
    if (EPI == 0) {
#pragma unroll
        for (int m = 0; m < 4; ++m) {
            int rbase = row0 + wr * 64 + m * 16 + crow;
#pragma unroll
            for (int n = 0; n < 4; ++n) {
                int col = col0 + wc * 64 + n * 16 + ccol;
                f32x4 v = acc[m][n];
#pragma unroll
                for (int r = 0; r < 4; ++r)
                    Cbf[(size_t)(rbase + r) * 1024 + col] = f2bf(v[r]);
            }
        }
    } else {
        const size_t NOUT = (size_t)NNODES * OUTCH;
#pragma unroll
        for (int n = 0; n < 4; ++n) {
            int col = col0 + wc * 64 + n * 16 + ccol;
            bool lo = col < OUTCH;
            int colo = lo ? col : col - OUTCH;
            float bias = lo ? bm[colo] : bs[colo];
#pragma unroll
            for (int m = 0; m < 4; ++m) {
                int rbase = row0 + wr * 64 + m * 16 + crow;
                f32x4 v = acc[m][n];
#pragma unroll
                for (int r = 0; r < 4; ++r) {
                    int rr = rbase + r;
                    if (rr < NNODES) {
                        float val = v[r] + bias;
                        if (lo) {
                            out[(size_t)rr * OUTCH + colo] = val;
                            out[NOUT + (size_t)rr * OUTCH + colo] = val;
                        } else {
                            out[2 * NOUT + (size_t)rr * OUTCH + colo] = val;
                        }
                    }
                }
            }
        }
    }
}

extern "C" void kernel_launch(void* const* d_in, const int* in_sizes, int n_in,
                              void* d_out, int out_size, void* d_ws, size_t ws_size,
                              hipStream_t stream) {
    const float* x   = (const float*)d_in[0];
    const int*   ei  = (const int*)d_in[1];
    const float* W1  = (const float*)d_in[2];
    const float* b1  = (const float*)d_in[3];
    const float* Wm  = (const float*)d_in[4];
    const float* bm  = (const float*)d_in[5];
    const float* Ws  = (const float*)d_in[6];
    const float* bs  = (const float*)d_in[7];
    const float* gw  = (const float*)d_in[8];
    const float* gb  = (const float*)d_in[9];
    const float* gms = (const float*)d_in[10];
    const int* srcI = ei;
    const int* dstI = ei + NEDGES;

    char* ws = (char*)d_ws;
    const size_t SBIG = (size_t)MPAD * 1024 * 2;
    u16* xn   = (u16*)(ws);
    u16* h1g  = (u16*)(ws + SBIG);
    u16* h    = (u16*)(ws + 2 * SBIG);
    u16* aggh = xn;                                 // xn dead after gemm1
    u16* Bt1  = (u16*)(ws + 3 * SBIG);
    u16* Bt2  = (u16*)(ws + 3 * SBIG + (size_t)2 * 1024 * 1024);
    // partial stats live inside h1g's buffer (dead until gemm1, consumed before)
    float* psum  = (float*)(ws + SBIG);                              // 2.56 MB
    float* psq   = (float*)(ws + SBIG + (size_t)NSB * 4096);         // 2.56 MB
    float* psum2 = (float*)(ws + SBIG + (size_t)2 * NSB * 4096);     // 128 KB
    float* psq2  = (float*)(ws + SBIG + (size_t)2 * NSB * 4096 + (size_t)NSB2 * 4096); // 128 KB
    char* small   = ws + 3 * SBIG + (size_t)4 * 1024 * 1024;
    // zeroed region: cnt | rowsum | c1
    int*   cnt    = (int*)(small);                   // 40960
    float* rowsum = (float*)(small + 40960);         // 40960
    float* c1     = (float*)(small + 81920);         // 4096
    // non-zeroed:
    int*   row_ptr= (int*)(small + 86016);           // 40960
    int*   cursor = (int*)(small + 126976);          // 40960
    float* dis    = (float*)(small + 167936);        // 40960
    int*   csr_src= (int*)(small + 208896);          // 640000
    float* csr_w  = (float*)(small + 848896);        // 640000
    float* sc     = (float*)(small + 1488896);       // 4096
    float* sh     = (float*)(small + 1492992);       // 4096

    hipMemsetAsync(small, 0, 86016, stream);

    cast_stats_k<<<NSB, 256, 0, stream>>>(x, xn, psum, psq);  // absorbs poison drain
    deg_k<<<625, 256, 0, stream>>>(dstI, cnt);
    dis_k<<<40, 256, 0, stream>>>(cnt, dis, rowsum);
    scan_k<<<1, 256, 0, stream>>>(cnt, row_ptr, cursor);
    fill_k<<<625, 256, 0, stream>>>(srcI, dstI, dis, cursor, csr_src, csr_w, rowsum);
    reduce1_k<<<NSB2, 256, 0, stream>>>(psum, psq, psum2, psq2);
    scale2_k<<<4, 256, 0, stream>>>(psum2, psq2, gms, gw, gb, sc, sh);
    wt1_k<<<dim3(16, 16), 256, 0, stream>>>(W1, sc, Bt1);
    c1_k<<<dim3(4, 8), 256, 0, stream>>>(W1, sh, c1);
    wt2_k<<<dim3(16, 16), 256, 0, stream>>>(Wm, Ws, Bt2);

    gemm_k<0><<<dim3(8, 79), 256, 0, stream>>>(xn, Bt1, h1g, nullptr, nullptr, nullptr);
    agg_k<1><<<NNODES, 256, 0, stream>>>(h1g, h, row_ptr, csr_src, csr_w, dis, b1, rowsum, c1);
    agg_k<0><<<NNODES, 256, 0, stream>>>(h, aggh, row_ptr, csr_src, csr_w, dis, nullptr, nullptr, nullptr);
    gemm_k<1><<<dim3(8, 79), 256, 0, stream>>>(aggh, Bt2, nullptr, (float*)d_out, bm, bs);
}

// Round 6
// 376.119 us; speedup vs baseline: 1.1549x; 1.0192x over previous
//
#include <hip/hip_runtime.h>
#include <hip/hip_bf16.h>
#include <stdint.h>

#define NNODES 10000
#define NEDGES 160000
#define INCH 1024
#define HCH 1024
#define OUTCH 512
#define MPAD 10112           // 79 * 128
#define EPSV 1e-5f
#define NEG 0.1f
#define NSB 625              // stat blocks
#define NSB2 32              // second-level stat blocks

typedef unsigned short u16;
typedef __bf16 bf16x8 __attribute__((ext_vector_type(8)));
typedef float f32x4 __attribute__((ext_vector_type(4)));
typedef __attribute__((address_space(1))) unsigned int gu32;
typedef __attribute__((address_space(3))) unsigned int lu32;

#define GL16(g, l) __builtin_amdgcn_global_load_lds((const gu32*)(g), (lu32*)(l), 16, 0, 0)

__device__ __forceinline__ float bf2f(u16 u) {
    union { unsigned int i; float f; } v; v.i = ((unsigned int)u) << 16; return v.f;
}
__device__ __forceinline__ u16 f2bf(float f) {
    union { float f; unsigned int i; } v; v.f = f;
    unsigned int r = v.i + 0x7fffu + ((v.i >> 16) & 1u);
    return (u16)(r >> 16);
}

// ---------- fused cast fp32->bf16 + per-block column stats (NO atomics) ----------
__global__ __launch_bounds__(256) void cast_stats_k(const float* __restrict__ x,
                                                    u16* __restrict__ xn,
                                                    float* __restrict__ psum,
                                                    float* __restrict__ psq) {
    int c = threadIdx.x * 4;
    int r0 = blockIdx.x * 16;
    float s0 = 0.f, s1 = 0.f, s2 = 0.f, s3 = 0.f;
    float q0 = 0.f, q1 = 0.f, q2 = 0.f, q3 = 0.f;
#pragma unroll
    for (int r = 0; r < 16; ++r) {
        size_t off = (size_t)(r0 + r) * INCH + c;
        float4 v = *(const float4*)(x + off);
        ushort4 o;
        o.x = f2bf(v.x); o.y = f2bf(v.y); o.z = f2bf(v.z); o.w = f2bf(v.w);
        *(ushort4*)(xn + off) = o;
        float f0 = bf2f(o.x), f1 = bf2f(o.y), f2 = bf2f(o.z), f3 = bf2f(o.w);
        s0 += f0; s1 += f1; s2 += f2; s3 += f3;
        q0 += f0 * f0; q1 += f1 * f1; q2 += f2 * f2; q3 += f3 * f3;
    }
    size_t pb = (size_t)blockIdx.x * 1024 + c;
    *(float4*)(psum + pb) = make_float4(s0, s1, s2, s3);
    *(float4*)(psq + pb)  = make_float4(q0, q1, q2, q3);
}

// ---------- stage-1 reduce: 625 partials -> 32 partials ----------
__global__ __launch_bounds__(256) void reduce1_k(const float* __restrict__ psum,
                                                 const float* __restrict__ psq,
                                                 float* __restrict__ psum2,
                                                 float* __restrict__ psq2) {
    int c = threadIdx.x * 4;
    int b0 = blockIdx.x * 20;
    int b1 = min(b0 + 20, NSB);
    f32x4 s = {0.f, 0.f, 0.f, 0.f}, q = {0.f, 0.f, 0.f, 0.f};
    for (int b = b0; b < b1; ++b) {
        f32x4 vs = *(const f32x4*)(psum + (size_t)b * 1024 + c);
        f32x4 vq = *(const f32x4*)(psq + (size_t)b * 1024 + c);
        s += vs; q += vq;
    }
    *(f32x4*)(psum2 + (size_t)blockIdx.x * 1024 + c) = s;
    *(f32x4*)(psq2 + (size_t)blockIdx.x * 1024 + c) = q;
}

// ---------- stage-2: reduce 32 partials -> per-column scale/shift ----------
__global__ __launch_bounds__(256) void scale2_k(const float* __restrict__ psum2,
                                                const float* __restrict__ psq2,
                                                const float* __restrict__ gms,
                                                const float* __restrict__ gw,
                                                const float* __restrict__ gb,
                                                float* __restrict__ sc, float* __restrict__ sh) {
    int c = blockIdx.x * 256 + threadIdx.x;   // 0..1023
    float s = 0.f, q = 0.f;
#pragma unroll
    for (int b = 0; b < NSB2; ++b) {
        s += psum2[(size_t)b * 1024 + c];
        q += psq2[(size_t)b * 1024 + c];
    }
    const float invn = 1.0f / NNODES;
    float m = s * invn;
    float msq = q * invn;
    float g = gms[c];
    float var = msq - g * (2.0f - g) * m * m;
    float scale = rsqrtf(var + EPSV) * gw[c];
    sc[c] = scale;
    sh[c] = gb[c] - g * m * scale;
}

// ---------- rank-1 correction vector: c1[j] = sum_k sh[k] * W1[k,j] ----------
__global__ void c1_k(const float* __restrict__ W1, const float* __restrict__ sh,
                     float* __restrict__ c1) {
    int j = blockIdx.x * 256 + threadIdx.x;
    int k0 = blockIdx.y * 128;
    float a = 0.f;
#pragma unroll 4
    for (int k = k0; k < k0 + 128; ++k) a += sh[k] * W1[(size_t)k * HCH + j];
    atomicAdd(&c1[j], a);
}

// ---------- weight convert: LDS-tiled transpose, W1 rows scaled by sc[k] ----------
__global__ __launch_bounds__(256) void wt1_k(const float* __restrict__ W,
                                             const float* __restrict__ sc,
                                             u16* __restrict__ Bt) {
    __shared__ u16 t[64][68];
    int k0 = blockIdx.y * 64, c0 = blockIdx.x * 64;
    int tc = (threadIdx.x & 15) * 4;
    int tk = threadIdx.x >> 4;
#pragma unroll
    for (int i = 0; i < 64; i += 16) {
        float scr = sc[k0 + tk + i];
        float4 v = *(const float4*)(W + (size_t)(k0 + tk + i) * HCH + c0 + tc);
        t[tc + 0][tk + i] = f2bf(v.x * scr);
        t[tc + 1][tk + i] = f2bf(v.y * scr);
        t[tc + 2][tk + i] = f2bf(v.z * scr);
        t[tc + 3][tk + i] = f2bf(v.w * scr);
    }
    __syncthreads();
    int wk = (threadIdx.x & 15) * 4;
    int wc = threadIdx.x >> 4;
#pragma unroll
    for (int i = 0; i < 64; i += 16) {
        ushort4 o;
        o.x = t[wc + i][wk + 0]; o.y = t[wc + i][wk + 1];
        o.z = t[wc + i][wk + 2]; o.w = t[wc + i][wk + 3];
        *(ushort4*)(Bt + (size_t)(c0 + wc + i) * 1024 + k0 + wk) = o;
    }
}

__global__ __launch_bounds__(256) void wt2_k(const float* __restrict__ Wm,
                                             const float* __restrict__ Ws,
                                             u16* __restrict__ Bt) {
    __shared__ u16 t[64][68];
    int k0 = blockIdx.y * 64, c0 = blockIdx.x * 64;
    const float* W = (c0 < OUTCH) ? Wm : Ws;
    int cb = (c0 < OUTCH) ? c0 : c0 - OUTCH;
    int tc = (threadIdx.x & 15) * 4;
    int tk = threadIdx.x >> 4;
#pragma unroll
    for (int i = 0; i < 64; i += 16) {
        float4 v = *(const float4*)(W + (size_t)(k0 + tk + i) * OUTCH + cb + tc);
        t[tc + 0][tk + i] = f2bf(v.x);
        t[tc + 1][tk + i] = f2bf(v.y);
        t[tc + 2][tk + i] = f2bf(v.z);
        t[tc + 3][tk + i] = f2bf(v.w);
    }
    __syncthreads();
    int wk = (threadIdx.x & 15) * 4;
    int wc = threadIdx.x >> 4;
#pragma unroll
    for (int i = 0; i < 64; i += 16) {
        ushort4 o;
        o.x = t[wc + i][wk + 0]; o.y = t[wc + i][wk + 1];
        o.z = t[wc + i][wk + 2]; o.w = t[wc + i][wk + 3];
        *(ushort4*)(Bt + (size_t)(c0 + wc + i) * 1024 + k0 + wk) = o;
    }
}

// ---------- CSR build ----------
__global__ void deg_k(const int* __restrict__ dst, int* __restrict__ cnt) {
    int e = blockIdx.x * 256 + threadIdx.x;
    if (e < NEDGES) atomicAdd(&cnt[dst[e]], 1);
}
__global__ void dis_k(const int* __restrict__ cnt, float* __restrict__ dis,
                      float* __restrict__ rowsum) {
    int i = blockIdx.x * 256 + threadIdx.x;
    if (i < NNODES) {
        float d = rsqrtf((float)(cnt[i] + 1));
        dis[i] = d;
        rowsum[i] = d * d;
    }
}
__global__ void scan_k(const int* __restrict__ cnt, int* __restrict__ row_ptr,
                       int* __restrict__ cursor) {
    __shared__ int sm[256];
    int tid = threadIdx.x;
    const int per = 40;
    int base = tid * per;
    int s = 0;
    for (int i = 0; i < per; ++i) { int idx = base + i; if (idx < NNODES) s += cnt[idx]; }
    sm[tid] = s; __syncthreads();
    for (int off = 1; off < 256; off <<= 1) {
        int v = (tid >= off) ? sm[tid - off] : 0;
        __syncthreads();
        sm[tid] += v;
        __syncthreads();
    }
    int run = (tid == 0) ? 0 : sm[tid - 1];
    for (int i = 0; i < per; ++i) {
        int idx = base + i;
        if (idx < NNODES) { row_ptr[idx] = run; cursor[idx] = run; run += cnt[idx]; }
    }
    if (tid == 255) row_ptr[NNODES] = sm[255];
}
// packed CSR entry: .x = src node, .y = bitcast weight
__global__ void fill_k(const int* __restrict__ src, const int* __restrict__ dst,
                       const float* __restrict__ dis, int* __restrict__ cursor,
                       int2* __restrict__ csr, float* __restrict__ rowsum) {
    int e = blockIdx.x * 256 + threadIdx.x;
    if (e >= NEDGES) return;
    int s = src[e], d = dst[e];
    float w = dis[s] * dis[d];
    int pos = atomicAdd(&cursor[d], 1);
    csr[pos] = make_int2(s, __float_as_int(w));
    atomicAdd(&rowsum[d], w);
}

// ---------- aggregation: 4-way edge-unrolled for MLP ----------
// MODE 1: += rowsum*c1 + b1, then leaky_relu
template<int MODE>
__global__ __launch_bounds__(256) void agg_k(const u16* __restrict__ in, u16* __restrict__ out,
                      const int* __restrict__ row_ptr, const int2* __restrict__ csr,
                      const float* __restrict__ dis,
                      const float* __restrict__ bias, const float* __restrict__ rowsum,
                      const float* __restrict__ c1) {
    int node = blockIdx.x;
    int c = threadIdx.x * 4;
    float dv = dis[node];
    float selfw = dv * dv;
    const size_t base = 0;
    ushort4 sv = *(const ushort4*)(in + (size_t)node * HCH + c);
    f32x4 a0 = {bf2f(sv.x) * selfw, bf2f(sv.y) * selfw, bf2f(sv.z) * selfw, bf2f(sv.w) * selfw};
    f32x4 a1 = {0.f, 0.f, 0.f, 0.f};
    f32x4 a2 = {0.f, 0.f, 0.f, 0.f};
    f32x4 a3 = {0.f, 0.f, 0.f, 0.f};
    int e0 = row_ptr[node], e1 = row_ptr[node + 1];
    int e = e0;
    for (; e + 4 <= e1; e += 4) {
        int2 sw0 = csr[e + 0];
        int2 sw1 = csr[e + 1];
        int2 sw2 = csr[e + 2];
        int2 sw3 = csr[e + 3];
        ushort4 v0 = *(const ushort4*)(in + (size_t)sw0.x * HCH + c);
        ushort4 v1 = *(const ushort4*)(in + (size_t)sw1.x * HCH + c);
        ushort4 v2 = *(const ushort4*)(in + (size_t)sw2.x * HCH + c);
        ushort4 v3 = *(const ushort4*)(in + (size_t)sw3.x * HCH + c);
        float w0 = __int_as_float(sw0.y), w1 = __int_as_float(sw1.y);
        float w2 = __int_as_float(sw2.y), w3 = __int_as_float(sw3.y);
        a0 += (f32x4){bf2f(v0.x), bf2f(v0.y), bf2f(v0.z), bf2f(v0.w)} * w0;
        a1 += (f32x4){bf2f(v1.x), bf2f(v1.y), bf2f(v1.z), bf2f(v1.w)} * w1;
        a2 += (f32x4){bf2f(v2.x), bf2f(v2.y), bf2f(v2.z), bf2f(v2.w)} * w2;
        a3 += (f32x4){bf2f(v3.x), bf2f(v3.y), bf2f(v3.z), bf2f(v3.w)} * w3;
    }
    for (; e < e1; ++e) {
        int2 sw = csr[e];
        float w = __int_as_float(sw.y);
        ushort4 v = *(const ushort4*)(in + (size_t)sw.x * HCH + c);
        a0 += (f32x4){bf2f(v.x), bf2f(v.y), bf2f(v.z), bf2f(v.w)} * w;
    }
    f32x4 a = (a0 + a1) + (a2 + a3);
    if (MODE == 1) {
        float rs = rowsum[node];
        float4 b = *(const float4*)(bias + c);
        float4 cc = *(const float4*)(c1 + c);
        a[0] += rs * cc.x + b.x; a[1] += rs * cc.y + b.y;
        a[2] += rs * cc.z + b.z; a[3] += rs * cc.w + b.w;
        a[0] = a[0] > 0.f ? a[0] : NEG * a[0];
        a[1] = a[1] > 0.f ? a[1] : NEG * a[1];
        a[2] = a[2] > 0.f ? a[2] : NEG * a[2];
        a[3] = a[3] > 0.f ? a[3] : NEG * a[3];
    }
    ushort4 o; o.x = f2bf(a[0]); o.y = f2bf(a[1]); o.z = f2bf(a[2]); o.w = f2bf(a[3]);
    *(ushort4*)(out + (size_t)node * HCH + c) = o;
}

// ---------- bf16 MFMA GEMM ----------
template<int EPI>
__global__ __launch_bounds__(256) void gemm_k(
    const u16* __restrict__ A, const u16* __restrict__ Bt,
    u16* __restrict__ Cbf, float* __restrict__ out,
    const float* __restrict__ bm, const float* __restrict__ bs) {
    __shared__ u16 As[128 * 32];
    __shared__ u16 Bs[128 * 32];
    const int tid = threadIdx.x;
    const int wave = tid >> 6;
    const int lane = tid & 63;
    const int row0 = blockIdx.y * 128;
    const int col0 = blockIdx.x * 128;
    const int wr = wave >> 1, wc = wave & 1;
    const int sr = lane >> 2;
    const int sc = (lane & 3) * 8;
    u16* AsW0 = &As[(wave * 16) * 32];
    u16* AsW1 = &As[(64 + wave * 16) * 32];
    u16* BsW0 = &Bs[(wave * 16) * 32];
    u16* BsW1 = &Bs[(64 + wave * 16) * 32];
    const u16* Ag0 = A + (size_t)(row0 + wave * 16 + sr) * 1024 + sc;
    const u16* Ag1 = A + (size_t)(row0 + 64 + wave * 16 + sr) * 1024 + sc;
    const u16* Bg0 = Bt + (size_t)(col0 + wave * 16 + sr) * 1024 + sc;
    const u16* Bg1 = Bt + (size_t)(col0 + 64 + wave * 16 + sr) * 1024 + sc;

    f32x4 acc[4][4] = {};
    const int arow = lane & 15;
    const int ak = (lane >> 4) * 8;
    for (int kk = 0; kk < 1024; kk += 32) {
        GL16(Ag0 + kk, AsW0);
        GL16(Ag1 + kk, AsW1);
        GL16(Bg0 + kk, BsW0);
        GL16(Bg1 + kk, BsW1);
        __syncthreads();
        bf16x8 af[4], bf[4];
#pragma unroll
        for (int m = 0; m < 4; ++m)
            af[m] = *reinterpret_cast<const bf16x8*>(&As[(wr * 64 + m * 16 + arow) * 32 + ak]);
#pragma unroll
        for (int n = 0; n < 4; ++n)
            bf[n] = *reinterpret_cast<const bf16x8*>(&Bs[(wc * 64 + n * 16 + arow) * 32 + ak]);
#pragma unroll
        for (int m = 0; m < 4; ++m)
#pragma unroll
            for (int n = 0; n < 4; ++n)
                acc[m][n] = __builtin_amdgcn_mfma_f32_16x16x32_bf16(af[m], bf[n], acc[m][n], 0, 0, 0);
        __syncthreads();
    }
    const int crow = (lane >> 4) * 4;
    const int ccol = lane & 15;
    if (EPI == 0) {
#pragma unroll
        for (int m = 0; m < 4; ++m) {
            int rbase = row0 + wr * 64 + m * 16 + crow;
#pragma unroll
            for (int n = 0; n < 4; ++n) {
                int col = col0 + wc * 64 + n * 16 + ccol;
                f32x4 v = acc[m][n];
#pragma unroll
                for (int r = 0; r < 4; ++r)
                    Cbf[(size_t)(rbase + r) * 1024 + col] = f2bf(v[r]);
            }
        }
    } else {
        const size_t NOUT = (size_t)NNODES * OUTCH;
#pragma unroll
        for (int n = 0; n < 4; ++n) {
            int col = col0 + wc * 64 + n * 16 + ccol;
            bool lo = col < OUTCH;
            int colo = lo ? col : col - OUTCH;
            float bias = lo ? bm[colo] : bs[colo];
#pragma unroll
            for (int m = 0; m < 4; ++m) {
                int rbase = row0 + wr * 64 + m * 16 + crow;
                f32x4 v = acc[m][n];
#pragma unroll
                for (int r = 0; r < 4; ++r) {
                    int rr = rbase + r;
                    if (rr < NNODES) {
                        float val = v[r] + bias;
                        if (lo) {
                            out[(size_t)rr * OUTCH + colo] = val;
                            out[NOUT + (size_t)rr * OUTCH + colo] = val;
                        } else {
                            out[2 * NOUT + (size_t)rr * OUTCH + colo] = val;
                        }
                    }
                }
            }
        }
    }
}

extern "C" void kernel_launch(void* const* d_in, const int* in_sizes, int n_in,
                              void* d_out, int out_size, void* d_ws, size_t ws_size,
                              hipStream_t stream) {
    const float* x   = (const float*)d_in[0];
    const int*   ei  = (const int*)d_in[1];
    const float* W1  = (const float*)d_in[2];
    const float* b1  = (const float*)d_in[3];
    const float* Wm  = (const float*)d_in[4];
    const float* bm  = (const float*)d_in[5];
    const float* Ws  = (const float*)d_in[6];
    const float* bs  = (const float*)d_in[7];
    const float* gw  = (const float*)d_in[8];
    const float* gb  = (const float*)d_in[9];
    const float* gms = (const float*)d_in[10];
    const int* srcI = ei;
    const int* dstI = ei + NEDGES;

    char* ws = (char*)d_ws;
    const size_t SBIG = (size_t)MPAD * 1024 * 2;
    u16* xn   = (u16*)(ws);
    u16* h1g  = (u16*)(ws + SBIG);
    u16* h    = (u16*)(ws + 2 * SBIG);
    u16* aggh = xn;                                 // xn dead after gemm1
    u16* Bt1  = (u16*)(ws + 3 * SBIG);
    u16* Bt2  = (u16*)(ws + 3 * SBIG + (size_t)2 * 1024 * 1024);
    // partial stats live inside h1g's buffer (dead until gemm1, consumed before)
    float* psum  = (float*)(ws + SBIG);                              // 2.56 MB
    float* psq   = (float*)(ws + SBIG + (size_t)NSB * 4096);         // 2.56 MB
    float* psum2 = (float*)(ws + SBIG + (size_t)2 * NSB * 4096);     // 128 KB
    float* psq2  = (float*)(ws + SBIG + (size_t)2 * NSB * 4096 + (size_t)NSB2 * 4096); // 128 KB
    char* small   = ws + 3 * SBIG + (size_t)4 * 1024 * 1024;
    // zeroed region: cnt | rowsum | c1
    int*   cnt    = (int*)(small);                   // 40960
    float* rowsum = (float*)(small + 40960);         // 40960
    float* c1     = (float*)(small + 81920);         // 4096
    // non-zeroed:
    int*   row_ptr= (int*)(small + 86016);           // 40960
    int*   cursor = (int*)(small + 126976);          // 40960
    float* dis    = (float*)(small + 167936);        // 40960
    int2*  csr    = (int2*)(small + 208896);         // 1,280,000
    float* sc     = (float*)(small + 1488896);       // 4096
    float* sh     = (float*)(small + 1492992);       // 4096

    hipMemsetAsync(small, 0, 86016, stream);

    cast_stats_k<<<NSB, 256, 0, stream>>>(x, xn, psum, psq);  // absorbs poison drain
    deg_k<<<625, 256, 0, stream>>>(dstI, cnt);
    dis_k<<<40, 256, 0, stream>>>(cnt, dis, rowsum);
    scan_k<<<1, 256, 0, stream>>>(cnt, row_ptr, cursor);
    fill_k<<<625, 256, 0, stream>>>(srcI, dstI, dis, cursor, csr, rowsum);
    reduce1_k<<<NSB2, 256, 0, stream>>>(psum, psq, psum2, psq2);
    scale2_k<<<4, 256, 0, stream>>>(psum2, psq2, gms, gw, gb, sc, sh);
    wt1_k<<<dim3(16, 16), 256, 0, stream>>>(W1, sc, Bt1);
    c1_k<<<dim3(4, 8), 256, 0, stream>>>(W1, sh, c1);
    wt2_k<<<dim3(16, 16), 256, 0, stream>>>(Wm, Ws, Bt2);

    gemm_k<0><<<dim3(8, 79), 256, 0, stream>>>(xn, Bt1, h1g, nullptr, nullptr, nullptr);
    agg_k<1><<<NNODES, 256, 0, stream>>>(h1g, h, row_ptr, csr, dis, b1, rowsum, c1);
    agg_k<0><<<NNODES, 256, 0, stream>>>(h, aggh, row_ptr, csr, dis, nullptr, nullptr, nullptr);
    gemm_k<1><<<dim3(8, 79), 256, 0, stream>>>(aggh, Bt2, nullptr, (float*)d_out, bm, bs);
}

// Round 7
// 369.946 us; speedup vs baseline: 1.1741x; 1.0167x over previous
//
#include <hip/hip_runtime.h>
#include <hip/hip_bf16.h>
#include <stdint.h>

#define NNODES 10000
#define NEDGES 160000
#define INCH 1024
#define HCH 1024
#define OUTCH 512
#define MPAD 10112           // 79 * 128
#define EPSV 1e-5f
#define NEG 0.1f
#define NSB 625              // stat blocks
#define NSB2 32              // second-level stat blocks

typedef unsigned short u16;
typedef __bf16 bf16x8 __attribute__((ext_vector_type(8)));
typedef float f32x4 __attribute__((ext_vector_type(4)));
typedef __attribute__((address_space(1))) unsigned int gu32;
typedef __attribute__((address_space(3))) unsigned int lu32;

#define GL16(g, l) __builtin_amdgcn_global_load_lds((const gu32*)(g), (lu32*)(l), 16, 0, 0)

__device__ __forceinline__ float bf2f(u16 u) {
    union { unsigned int i; float f; } v; v.i = ((unsigned int)u) << 16; return v.f;
}
__device__ __forceinline__ u16 f2bf(float f) {
    union { float f; unsigned int i; } v; v.f = f;
    unsigned int r = v.i + 0x7fffu + ((v.i >> 16) & 1u);
    return (u16)(r >> 16);
}

// ---------- fused cast fp32->bf16 + per-block column stats (NO atomics) ----------
__global__ __launch_bounds__(256) void cast_stats_k(const float* __restrict__ x,
                                                    u16* __restrict__ xn,
                                                    float* __restrict__ psum,
                                                    float* __restrict__ psq) {
    int c = threadIdx.x * 4;
    int r0 = blockIdx.x * 16;
    float s0 = 0.f, s1 = 0.f, s2 = 0.f, s3 = 0.f;
    float q0 = 0.f, q1 = 0.f, q2 = 0.f, q3 = 0.f;
#pragma unroll
    for (int r = 0; r < 16; ++r) {
        size_t off = (size_t)(r0 + r) * INCH + c;
        float4 v = *(const float4*)(x + off);
        ushort4 o;
        o.x = f2bf(v.x); o.y = f2bf(v.y); o.z = f2bf(v.z); o.w = f2bf(v.w);
        *(ushort4*)(xn + off) = o;
        float f0 = bf2f(o.x), f1 = bf2f(o.y), f2 = bf2f(o.z), f3 = bf2f(o.w);
        s0 += f0; s1 += f1; s2 += f2; s3 += f3;
        q0 += f0 * f0; q1 += f1 * f1; q2 += f2 * f2; q3 += f3 * f3;
    }
    size_t pb = (size_t)blockIdx.x * 1024 + c;
    *(float4*)(psum + pb) = make_float4(s0, s1, s2, s3);
    *(float4*)(psq + pb)  = make_float4(q0, q1, q2, q3);
}

// ---------- stage-1 reduce: 625 partials -> 32 partials ----------
__global__ __launch_bounds__(256) void reduce1_k(const float* __restrict__ psum,
                                                 const float* __restrict__ psq,
                                                 float* __restrict__ psum2,
                                                 float* __restrict__ psq2) {
    int c = threadIdx.x * 4;
    int b0 = blockIdx.x * 20;
    int b1 = min(b0 + 20, NSB);
    f32x4 s = {0.f, 0.f, 0.f, 0.f}, q = {0.f, 0.f, 0.f, 0.f};
    for (int b = b0; b < b1; ++b) {
        f32x4 vs = *(const f32x4*)(psum + (size_t)b * 1024 + c);
        f32x4 vq = *(const f32x4*)(psq + (size_t)b * 1024 + c);
        s += vs; q += vq;
    }
    *(f32x4*)(psum2 + (size_t)blockIdx.x * 1024 + c) = s;
    *(f32x4*)(psq2 + (size_t)blockIdx.x * 1024 + c) = q;
}

// ---------- stage-2: reduce 32 partials -> per-column scale/shift ----------
__global__ __launch_bounds__(256) void scale2_k(const float* __restrict__ psum2,
                                                const float* __restrict__ psq2,
                                                const float* __restrict__ gms,
                                                const float* __restrict__ gw,
                                                const float* __restrict__ gb,
                                                float* __restrict__ sc, float* __restrict__ sh) {
    int c = blockIdx.x * 256 + threadIdx.x;   // 0..1023
    float s = 0.f, q = 0.f;
#pragma unroll
    for (int b = 0; b < NSB2; ++b) {
        s += psum2[(size_t)b * 1024 + c];
        q += psq2[(size_t)b * 1024 + c];
    }
    const float invn = 1.0f / NNODES;
    float m = s * invn;
    float msq = q * invn;
    float g = gms[c];
    float var = msq - g * (2.0f - g) * m * m;
    float scale = rsqrtf(var + EPSV) * gw[c];
    sc[c] = scale;
    sh[c] = gb[c] - g * m * scale;
}

// ---------- rank-1 correction vector: c1[j] = sum_k sh[k] * W1[k,j] ----------
__global__ void c1_k(const float* __restrict__ W1, const float* __restrict__ sh,
                     float* __restrict__ c1) {
    int j = blockIdx.x * 256 + threadIdx.x;
    int k0 = blockIdx.y * 128;
    float a = 0.f;
#pragma unroll 4
    for (int k = k0; k < k0 + 128; ++k) a += sh[k] * W1[(size_t)k * HCH + j];
    atomicAdd(&c1[j], a);
}

// ---------- weight convert: LDS-tiled transpose, W1 rows scaled by sc[k] ----------
__global__ __launch_bounds__(256) void wt1_k(const float* __restrict__ W,
                                             const float* __restrict__ sc,
                                             u16* __restrict__ Bt) {
    __shared__ u16 t[64][68];
    int k0 = blockIdx.y * 64, c0 = blockIdx.x * 64;
    int tc = (threadIdx.x & 15) * 4;
    int tk = threadIdx.x >> 4;
#pragma unroll
    for (int i = 0; i < 64; i += 16) {
        float scr = sc[k0 + tk + i];
        float4 v = *(const float4*)(W + (size_t)(k0 + tk + i) * HCH + c0 + tc);
        t[tc + 0][tk + i] = f2bf(v.x * scr);
        t[tc + 1][tk + i] = f2bf(v.y * scr);
        t[tc + 2][tk + i] = f2bf(v.z * scr);
        t[tc + 3][tk + i] = f2bf(v.w * scr);
    }
    __syncthreads();
    int wk = (threadIdx.x & 15) * 4;
    int wc = threadIdx.x >> 4;
#pragma unroll
    for (int i = 0; i < 64; i += 16) {
        ushort4 o;
        o.x = t[wc + i][wk + 0]; o.y = t[wc + i][wk + 1];
        o.z = t[wc + i][wk + 2]; o.w = t[wc + i][wk + 3];
        *(ushort4*)(Bt + (size_t)(c0 + wc + i) * 1024 + k0 + wk) = o;
    }
}

__global__ __launch_bounds__(256) void wt2_k(const float* __restrict__ Wm,
                                             const float* __restrict__ Ws,
                                             u16* __restrict__ Bt) {
    __shared__ u16 t[64][68];
    int k0 = blockIdx.y * 64, c0 = blockIdx.x * 64;
    const float* W = (c0 < OUTCH) ? Wm : Ws;
    int cb = (c0 < OUTCH) ? c0 : c0 - OUTCH;
    int tc = (threadIdx.x & 15) * 4;
    int tk = threadIdx.x >> 4;
#pragma unroll
    for (int i = 0; i < 64; i += 16) {
        float4 v = *(const float4*)(W + (size_t)(k0 + tk + i) * OUTCH + cb + tc);
        t[tc + 0][tk + i] = f2bf(v.x);
        t[tc + 1][tk + i] = f2bf(v.y);
        t[tc + 2][tk + i] = f2bf(v.z);
        t[tc + 3][tk + i] = f2bf(v.w);
    }
    __syncthreads();
    int wk = (threadIdx.x & 15) * 4;
    int wc = threadIdx.x >> 4;
#pragma unroll
    for (int i = 0; i < 64; i += 16) {
        ushort4 o;
        o.x = t[wc + i][wk + 0]; o.y = t[wc + i][wk + 1];
        o.z = t[wc + i][wk + 2]; o.w = t[wc + i][wk + 3];
        *(ushort4*)(Bt + (size_t)(c0 + wc + i) * 1024 + k0 + wk) = o;
    }
}

// ---------- CSR build ----------
__global__ void deg_k(const int* __restrict__ dst, int* __restrict__ cnt) {
    int e = blockIdx.x * 256 + threadIdx.x;
    if (e < NEDGES) atomicAdd(&cnt[dst[e]], 1);
}
__global__ void dis_k(const int* __restrict__ cnt, float* __restrict__ dis,
                      float* __restrict__ rowsum) {
    int i = blockIdx.x * 256 + threadIdx.x;
    if (i < NNODES) {
        float d = rsqrtf((float)(cnt[i] + 1));
        dis[i] = d;
        rowsum[i] = d * d;
    }
}
__global__ void scan_k(const int* __restrict__ cnt, int* __restrict__ row_ptr,
                       int* __restrict__ cursor) {
    __shared__ int sm[256];
    int tid = threadIdx.x;
    const int per = 40;
    int base = tid * per;
    int s = 0;
    for (int i = 0; i < per; ++i) { int idx = base + i; if (idx < NNODES) s += cnt[idx]; }
    sm[tid] = s; __syncthreads();
    for (int off = 1; off < 256; off <<= 1) {
        int v = (tid >= off) ? sm[tid - off] : 0;
        __syncthreads();
        sm[tid] += v;
        __syncthreads();
    }
    int run = (tid == 0) ? 0 : sm[tid - 1];
    for (int i = 0; i < per; ++i) {
        int idx = base + i;
        if (idx < NNODES) { row_ptr[idx] = run; cursor[idx] = run; run += cnt[idx]; }
    }
    if (tid == 255) row_ptr[NNODES] = sm[255];
}
// packed CSR entry: .x = src node, .y = bitcast weight
__global__ void fill_k(const int* __restrict__ src, const int* __restrict__ dst,
                       const float* __restrict__ dis, int* __restrict__ cursor,
                       int2* __restrict__ csr, float* __restrict__ rowsum) {
    int e = blockIdx.x * 256 + threadIdx.x;
    if (e >= NEDGES) return;
    int s = src[e], d = dst[e];
    float w = dis[s] * dis[d];
    int pos = atomicAdd(&cursor[d], 1);
    csr[pos] = make_int2(s, __float_as_int(w));
    atomicAdd(&rowsum[d], w);
}

// ---------- channel-sliced aggregation: slice = blockIdx.x%8 -> pinned to one XCD ----------
// Each XCD's gather window = 10000 x 128ch x 2B = 2.56 MB (L2-resident).
// One wave per (node, slice); lane owns 2 channels. MODE 1: += rowsum*c1 + b1, leaky.
template<int MODE>
__global__ __launch_bounds__(256) void aggs_k(const u16* __restrict__ in, u16* __restrict__ out,
                      const int* __restrict__ row_ptr, const int2* __restrict__ csr,
                      const float* __restrict__ dis,
                      const float* __restrict__ bias, const float* __restrict__ rowsum,
                      const float* __restrict__ c1) {
    int slice = blockIdx.x;                       // 0..7 (gridDim.x == 8 => linear%8 == slice)
    int node = blockIdx.y * 4 + (threadIdx.x >> 6);
    int lane = threadIdx.x & 63;
    int ch = slice * 128 + lane * 2;
    float dv = dis[node];
    float selfw = dv * dv;
    unsigned int sv = *(const unsigned int*)(in + (size_t)node * HCH + ch);
    float a0 = bf2f((u16)(sv & 0xffff)) * selfw;
    float a1 = bf2f((u16)(sv >> 16)) * selfw;
    float b0 = 0.f, b1v = 0.f, c0 = 0.f, c1v = 0.f, d0 = 0.f, d1 = 0.f, e0a = 0.f, e1a = 0.f;
    int e0 = row_ptr[node], e1 = row_ptr[node + 1];
    int e = e0;
    for (; e + 4 <= e1; e += 4) {
        int2 sw0 = csr[e + 0];
        int2 sw1 = csr[e + 1];
        int2 sw2 = csr[e + 2];
        int2 sw3 = csr[e + 3];
        unsigned int v0 = *(const unsigned int*)(in + (size_t)sw0.x * HCH + ch);
        unsigned int v1 = *(const unsigned int*)(in + (size_t)sw1.x * HCH + ch);
        unsigned int v2 = *(const unsigned int*)(in + (size_t)sw2.x * HCH + ch);
        unsigned int v3 = *(const unsigned int*)(in + (size_t)sw3.x * HCH + ch);
        float w0 = __int_as_float(sw0.y), w1 = __int_as_float(sw1.y);
        float w2 = __int_as_float(sw2.y), w3 = __int_as_float(sw3.y);
        a0 += bf2f((u16)(v0 & 0xffff)) * w0; a1 += bf2f((u16)(v0 >> 16)) * w0;
        b0 += bf2f((u16)(v1 & 0xffff)) * w1; b1v += bf2f((u16)(v1 >> 16)) * w1;
        c0 += bf2f((u16)(v2 & 0xffff)) * w2; c1v += bf2f((u16)(v2 >> 16)) * w2;
        d0 += bf2f((u16)(v3 & 0xffff)) * w3; d1 += bf2f((u16)(v3 >> 16)) * w3;
    }
    for (; e < e1; ++e) {
        int2 sw = csr[e];
        float w = __int_as_float(sw.y);
        unsigned int v = *(const unsigned int*)(in + (size_t)sw.x * HCH + ch);
        e0a += bf2f((u16)(v & 0xffff)) * w; e1a += bf2f((u16)(v >> 16)) * w;
    }
    float r0 = ((a0 + b0) + (c0 + d0)) + e0a;
    float r1 = ((a1 + b1v) + (c1v + d1)) + e1a;
    if (MODE == 1) {
        float rs = rowsum[node];
        float2 bb = *(const float2*)(bias + ch);
        float2 cc = *(const float2*)(c1 + ch);
        r0 += rs * cc.x + bb.x;
        r1 += rs * cc.y + bb.y;
        r0 = r0 > 0.f ? r0 : NEG * r0;
        r1 = r1 > 0.f ? r1 : NEG * r1;
    }
    unsigned int o = (unsigned int)f2bf(r0) | ((unsigned int)f2bf(r1) << 16);
    *(unsigned int*)(out + (size_t)node * HCH + ch) = o;
}

// ---------- bf16 MFMA GEMM, 1-D grid with bijective XCD swizzle ----------
// 632 blocks; wg = (orig%8)*79 + orig/8 -> each XCD owns ~10 consecutive row-tiles
// (A chunk 2.56 MB + B 2 MB ~ L2-resident).
template<int EPI>
__global__ __launch_bounds__(256) void gemm_k(
    const u16* __restrict__ A, const u16* __restrict__ Bt,
    u16* __restrict__ Cbf, float* __restrict__ out,
    const float* __restrict__ bm, const float* __restrict__ bs) {
    __shared__ u16 As[128 * 32];
    __shared__ u16 Bs[128 * 32];
    const int orig = blockIdx.x;
    const int wg = (orig & 7) * 79 + (orig >> 3);
    const int row0 = (wg >> 3) * 128;
    const int col0 = (wg & 7) * 128;
    const int tid = threadIdx.x;
    const int wave = tid >> 6;
    const int lane = tid & 63;
    const int wr = wave >> 1, wc = wave & 1;
    const int sr = lane >> 2;
    const int sc = (lane & 3) * 8;
    u16* AsW0 = &As[(wave * 16) * 32];
    u16* AsW1 = &As[(64 + wave * 16) * 32];
    u16* BsW0 = &Bs[(wave * 16) * 32];
    u16* BsW1 = &Bs[(64 + wave * 16) * 32];
    const u16* Ag0 = A + (size_t)(row0 + wave * 16 + sr) * 1024 + sc;
    const u16* Ag1 = A + (size_t)(row0 + 64 + wave * 16 + sr) * 1024 + sc;
    const u16* Bg0 = Bt + (size_t)(col0 + wave * 16 + sr) * 1024 + sc;
    const u16* Bg1 = Bt + (size_t)(col0 + 64 + wave * 16 + sr) * 1024 + sc;

    f32x4 acc[4][4] = {};
    const int arow = lane & 15;
    const int ak = (lane >> 4) * 8;
    for (int kk = 0; kk < 1024; kk += 32) {
        GL16(Ag0 + kk, AsW0);
        GL16(Ag1 + kk, AsW1);
        GL16(Bg0 + kk, BsW0);
        GL16(Bg1 + kk, BsW1);
        __syncthreads();
        bf16x8 af[4], bf[4];
#pragma unroll
        for (int m = 0; m < 4; ++m)
            af[m] = *reinterpret_cast<const bf16x8*>(&As[(wr * 64 + m * 16 + arow) * 32 + ak]);
#pragma unroll
        for (int n = 0; n < 4; ++n)
            bf[n] = *reinterpret_cast<const bf16x8*>(&Bs[(wc * 64 + n * 16 + arow) * 32 + ak]);
#pragma unroll
        for (int m = 0; m < 4; ++m)
#pragma unroll
            for (int n = 0; n < 4; ++n)
                acc[m][n] = __builtin_amdgcn_mfma_f32_16x16x32_bf16(af[m], bf[n], acc[m][n], 0, 0, 0);
        __syncthreads();
    }
    const int crow = (lane >> 4) * 4;
    const int ccol = lane & 15;
    if (EPI == 0) {
#pragma unroll
        for (int m = 0; m < 4; ++m) {
            int rbase = row0 + wr * 64 + m * 16 + crow;
#pragma unroll
            for (int n = 0; n < 4; ++n) {
                int col = col0 + wc * 64 + n * 16 + ccol;
                f32x4 v = acc[m][n];
#pragma unroll
                for (int r = 0; r < 4; ++r)
                    Cbf[(size_t)(rbase + r) * 1024 + col] = f2bf(v[r]);
            }
        }
    } else {
        const size_t NOUT = (size_t)NNODES * OUTCH;
#pragma unroll
        for (int n = 0; n < 4; ++n) {
            int col = col0 + wc * 64 + n * 16 + ccol;
            bool lo = col < OUTCH;
            int colo = lo ? col : col - OUTCH;
            float bias = lo ? bm[colo] : bs[colo];
#pragma unroll
            for (int m = 0; m < 4; ++m) {
                int rbase = row0 + wr * 64 + m * 16 + crow;
                f32x4 v = acc[m][n];
#pragma unroll
                for (int r = 0; r < 4; ++r) {
                    int rr = rbase + r;
                    if (rr < NNODES) {
                        float val = v[r] + bias;
                        if (lo) {
                            out[(size_t)rr * OUTCH + colo] = val;
                            out[NOUT + (size_t)rr * OUTCH + colo] = val;
                        } else {
                            out[2 * NOUT + (size_t)rr * OUTCH + colo] = val;
                        }
                    }
                }
            }
        }
    }
}

extern "C" void kernel_launch(void* const* d_in, const int* in_sizes, int n_in,
                              void* d_out, int out_size, void* d_ws, size_t ws_size,
                              hipStream_t stream) {
    const float* x   = (const float*)d_in[0];
    const int*   ei  = (const int*)d_in[1];
    const float* W1  = (const float*)d_in[2];
    const float* b1  = (const float*)d_in[3];
    const float* Wm  = (const float*)d_in[4];
    const float* bm  = (const float*)d_in[5];
    const float* Ws  = (const float*)d_in[6];
    const float* bs  = (const float*)d_in[7];
    const float* gw  = (const float*)d_in[8];
    const float* gb  = (const float*)d_in[9];
    const float* gms = (const float*)d_in[10];
    const int* srcI = ei;
    const int* dstI = ei + NEDGES;

    char* ws = (char*)d_ws;
    const size_t SBIG = (size_t)MPAD * 1024 * 2;
    u16* xn   = (u16*)(ws);
    u16* h1g  = (u16*)(ws + SBIG);
    u16* h    = (u16*)(ws + 2 * SBIG);
    u16* aggh = xn;                                 // xn dead after gemm1
    u16* Bt1  = (u16*)(ws + 3 * SBIG);
    u16* Bt2  = (u16*)(ws + 3 * SBIG + (size_t)2 * 1024 * 1024);
    // partial stats live inside h1g's buffer (dead until gemm1, consumed before)
    float* psum  = (float*)(ws + SBIG);                              // 2.56 MB
    float* psq   = (float*)(ws + SBIG + (size_t)NSB * 4096);         // 2.56 MB
    float* psum2 = (float*)(ws + SBIG + (size_t)2 * NSB * 4096);     // 128 KB
    float* psq2  = (float*)(ws + SBIG + (size_t)2 * NSB * 4096 + (size_t)NSB2 * 4096); // 128 KB
    char* small   = ws + 3 * SBIG + (size_t)4 * 1024 * 1024;
    // zeroed region: cnt | rowsum | c1
    int*   cnt    = (int*)(small);                   // 40960
    float* rowsum = (float*)(small + 40960);         // 40960
    float* c1     = (float*)(small + 81920);         // 4096
    // non-zeroed:
    int*   row_ptr= (int*)(small + 86016);           // 40960
    int*   cursor = (int*)(small + 126976);          // 40960
    float* dis    = (float*)(small + 167936);        // 40960
    int2*  csr    = (int2*)(small + 208896);         // 1,280,000
    float* sc     = (float*)(small + 1488896);       // 4096
    float* sh     = (float*)(small + 1492992);       // 4096

    hipMemsetAsync(small, 0, 86016, stream);

    cast_stats_k<<<NSB, 256, 0, stream>>>(x, xn, psum, psq);  // absorbs poison drain
    deg_k<<<625, 256, 0, stream>>>(dstI, cnt);
    dis_k<<<40, 256, 0, stream>>>(cnt, dis, rowsum);
    scan_k<<<1, 256, 0, stream>>>(cnt, row_ptr, cursor);
    fill_k<<<625, 256, 0, stream>>>(srcI, dstI, dis, cursor, csr, rowsum);
    reduce1_k<<<NSB2, 256, 0, stream>>>(psum, psq, psum2, psq2);
    scale2_k<<<4, 256, 0, stream>>>(psum2, psq2, gms, gw, gb, sc, sh);
    wt1_k<<<dim3(16, 16), 256, 0, stream>>>(W1, sc, Bt1);
    c1_k<<<dim3(4, 8), 256, 0, stream>>>(W1, sh, c1);
    wt2_k<<<dim3(16, 16), 256, 0, stream>>>(Wm, Ws, Bt2);

    gemm_k<0><<<632, 256, 0, stream>>>(xn, Bt1, h1g, nullptr, nullptr, nullptr);
    aggs_k<1><<<dim3(8, 2500), 256, 0, stream>>>(h1g, h, row_ptr, csr, dis, b1, rowsum, c1);
    aggs_k<0><<<dim3(8, 2500), 256, 0, stream>>>(h, aggh, row_ptr, csr, dis, nullptr, nullptr, nullptr);
    gemm_k<1><<<632, 256, 0, stream>>>(aggh, Bt2, nullptr, (float*)d_out, bm, bs);
}